// Round 11
// baseline (148.577 us; speedup 1.0000x reference)
//
#include <hip/hip_runtime.h>

// HTMM: C=32 states, L=4 fanout, M=128 symbols, DEPTH=7.
// Level starts: {0,1,5,21,85,341,1365,5461,21845}.
// R23 = R22 with two more BITWISE-PRESERVING latency cuts in k_down_p:
// (1) aspL: permanent LDS copy of the asp table. W_LOADUP reads it, and
//     P4's W-down reload becomes ds_read_b128 (~12cyc) instead of a
//     mid-chain global_load_dwordx4 stream (~200-400cyc) -- the last
//     global access on the serial path. Same grp<8 gating as R21/R22
//     (the passing record; untouched).
// (2) logBL: logB gets its own LDS home (regB keeps raw smB, never
//     overwritten). ALG (scr rows 0-31, dead after L3) and logBL writes
//     are issued right after the L3 barrier, overlapping L2/L1/root dots.
//     bX2/bX1 move to new scr rows 80-84. P4 shrinks to W-reload+barrier.
// P5/P6 read logs from logBL -- identical bits, identical expf(log) chain.
// LDS ~96KB < 160KB, still 1 block/CU. absmax stays 0.
// Decomposition: fill 39.4 (harness, fixed) + fixed ~15 + kernels ~40.

static constexpr int OFF_B4   = 0;      // level-4 betas [s*32+i] (8192 f)
static constexpr int OFF_PART = 8192;   // 256 doubles (512 f)
static constexpr int IC2      = 9760;   // 16 finalize counters, stride 32 ints
static constexpr int IROOT2   = 10272;  // finalize root counter
static constexpr int OFF_ASP  = 10304;  // asp, stride-132 layout (4224 f)
static constexpr int OFF_RB   = 14528;  // smB^T linear (4224 f)
static constexpr int OFF_LRB  = 18752;  // log smB^T (4224 f)
static constexpr int OFF_LSP  = 22976;  // log sPt (132 f, +pad)
static constexpr int OFF_ALG  = 23120;  // ALG rows [J*128+lane*4] (4096 f)
static constexpr int OFF_TBO  = 27216;  // per-block tbS, stride 672 (172032 f)
static constexpr size_t WS_NEED_BYTES = (size_t)(OFF_TBO + 256 * 672) * 4;

__device__ __forceinline__ float rsum32(float v) {
#pragma unroll
  for (int k = 1; k <= 16; k <<= 1) v += __shfl_xor(v, k);
  return v;
}
__device__ __forceinline__ void rsum32x2(float& a, float& b) {
#pragma unroll
  for (int k = 1; k <= 16; k <<= 1) { a += __shfl_xor(a, k); b += __shfl_xor(b, k); }
}
__device__ __forceinline__ void rsum32x4(float& a, float& b, float& c, float& d) {
#pragma unroll
  for (int k = 1; k <= 16; k <<= 1) {
    a += __shfl_xor(a, k); b += __shfl_xor(b, k);
    c += __shfl_xor(c, k); d += __shfl_xor(d, k);
  }
}
__device__ __forceinline__ float4 exp4f(float4 v) {
  return make_float4(__expf(v.x), __expf(v.y), __expf(v.z), __expf(v.w));
}

// ---------------- register-file W matrix: 32 named float4 ----------------
#define W_DECL float4 Wr0, Wr1, Wr2, Wr3, Wr4, Wr5, Wr6, Wr7, Wr8, Wr9,     \
    Wr10, Wr11, Wr12, Wr13, Wr14, Wr15, Wr16, Wr17, Wr18, Wr19, Wr20, Wr21, \
    Wr22, Wr23, Wr24, Wr25, Wr26, Wr27, Wr28, Wr29, Wr30, Wr31;

#define REPW(X) X(0,Wr0) X(1,Wr1) X(2,Wr2) X(3,Wr3) X(4,Wr4) X(5,Wr5)       \
    X(6,Wr6) X(7,Wr7) X(8,Wr8) X(9,Wr9) X(10,Wr10) X(11,Wr11) X(12,Wr12)    \
    X(13,Wr13) X(14,Wr14) X(15,Wr15) X(16,Wr16) X(17,Wr17) X(18,Wr18)       \
    X(19,Wr19) X(20,Wr20) X(21,Wr21) X(22,Wr22) X(23,Wr23) X(24,Wr24)       \
    X(25,Wr25) X(26,Wr26) X(27,Wr27) X(28,Wr28) X(29,Wr29) X(30,Wr30)       \
    X(31,Wr31)

#define REPQ(X) X(0,Wr0,Wr1,Wr2,Wr3) X(1,Wr4,Wr5,Wr6,Wr7)                   \
    X(2,Wr8,Wr9,Wr10,Wr11) X(3,Wr12,Wr13,Wr14,Wr15) X(4,Wr16,Wr17,Wr18,Wr19)\
    X(5,Wr20,Wr21,Wr22,Wr23) X(6,Wr24,Wr25,Wr26,Wr27) X(7,Wr28,Wr29,Wr30,Wr31)

// load up-orientation row (lane) from a stride-132 asp table
#define WLD_B(J, WJ) WJ = *(const float4*)(scrW_ + 4 * (J));
#define W_LOADUP { const float* scrW_ = scr + lane * 132; REPW(WLD_B) }
#define W_LOADUPA { const float* scrW_ = aspL + lane * 132; REPW(WLD_B) }

// load down-orientation from a stride-132 asp table (row J, cols 4lane..)
#define WLDDN_B(J, WJ) WJ = *(const float4*)(wsASP_ + (J) * 132 + lane * 4);

// tb = dot(W_row_lane, X[0..127])
#define DOT_B(J, WJ) { const float4 x_ = *(const float4*)(dXp_ + 4 * (J));   \
    dt0_ = fmaf(WJ.x, x_.x, dt0_); dt1_ = fmaf(WJ.y, x_.y, dt1_);            \
    dt2_ = fmaf(WJ.z, x_.z, dt2_); dt3_ = fmaf(WJ.w, x_.w, dt3_); }
#define DOT128M(OUT, XP) { const float* dXp_ = (XP);                         \
    float dt0_ = 0.f, dt1_ = 0.f, dt2_ = 0.f, dt3_ = 0.f;                    \
    REPW(DOT_B) (OUT) = (dt0_ + dt1_) + (dt2_ + dt3_); }

// two parents, shared W row
#define DOTX2_B(J, WJ) {                                                     \
    const float4 x_ = *(const float4*)(dXp0_ + 4 * (J));                     \
    const float4 y_ = *(const float4*)(dXp1_ + 4 * (J));                     \
    da0_ = fmaf(WJ.x, x_.x, da0_); db0_ = fmaf(WJ.x, y_.x, db0_);            \
    da1_ = fmaf(WJ.y, x_.y, da1_); db1_ = fmaf(WJ.y, y_.y, db1_);            \
    da2_ = fmaf(WJ.z, x_.z, da2_); db2_ = fmaf(WJ.z, y_.z, db2_);            \
    da3_ = fmaf(WJ.w, x_.w, da3_); db3_ = fmaf(WJ.w, y_.w, db3_); }
#define DOT128X2M(O0, O1, XP0, XP1) {                                        \
    const float* dXp0_ = (XP0); const float* dXp1_ = (XP1);                  \
    float da0_ = 0.f, da1_ = 0.f, da2_ = 0.f, da3_ = 0.f;                    \
    float db0_ = 0.f, db1_ = 0.f, db2_ = 0.f, db3_ = 0.f;                    \
    REPW(DOTX2_B) (O0) = (da0_ + da1_) + (da2_ + da3_);                      \
    (O1) = (db0_ + db1_) + (db2_ + db3_); }

// path walk: w only.  w_l += W[i].l * rb[i]
#define WO_B(Q, WA, WB, WC, WD) {                                            \
    const float4 rv_ = *(const float4*)(rbp_ + 4 * (Q));                     \
    ww0_ = fmaf(WA.x, rv_.x, ww0_); ww1_ = fmaf(WA.y, rv_.x, ww1_);          \
    ww2_ = fmaf(WA.z, rv_.x, ww2_); ww3_ = fmaf(WA.w, rv_.x, ww3_);          \
    ww0_ = fmaf(WB.x, rv_.y, ww0_); ww1_ = fmaf(WB.y, rv_.y, ww1_);          \
    ww2_ = fmaf(WB.z, rv_.y, ww2_); ww3_ = fmaf(WB.w, rv_.y, ww3_);          \
    ww0_ = fmaf(WC.x, rv_.z, ww0_); ww1_ = fmaf(WC.y, rv_.z, ww1_);          \
    ww2_ = fmaf(WC.z, rv_.z, ww2_); ww3_ = fmaf(WC.w, rv_.z, ww3_);          \
    ww0_ = fmaf(WD.x, rv_.w, ww0_); ww1_ = fmaf(WD.y, rv_.w, ww1_);          \
    ww2_ = fmaf(WD.z, rv_.w, ww2_); ww3_ = fmaf(WD.w, rv_.w, ww3_); }
#define WONLY128M(W, RBP) { const float* rbp_ = (RBP);                       \
    float ww0_ = 0.f, ww1_ = 0.f, ww2_ = 0.f, ww3_ = 0.f;                    \
    REPQ(WO_B) (W)[0] = ww0_; (W)[1] = ww1_; (W)[2] = ww2_; (W)[3] = ww3_; }

// w + u (u from ALG rows in scr)
#define WU_SUB(ROW, WX, RC) {                                                \
    const float4 av_ = *(const float4*)(ALGp_ + (ROW) * 128);                \
    ww0_ = fmaf(WX.x, RC, ww0_); uu0_ = fmaf(av_.x, RC, uu0_);               \
    ww1_ = fmaf(WX.y, RC, ww1_); uu1_ = fmaf(av_.y, RC, uu1_);               \
    ww2_ = fmaf(WX.z, RC, ww2_); uu2_ = fmaf(av_.z, RC, uu2_);               \
    ww3_ = fmaf(WX.w, RC, ww3_); uu3_ = fmaf(av_.w, RC, uu3_); }
#define WU_B(Q, WA, WB, WC, WD) {                                            \
    const float4 rv_ = *(const float4*)(rbp_ + 4 * (Q));                     \
    WU_SUB(4 * (Q) + 0, WA, rv_.x) WU_SUB(4 * (Q) + 1, WB, rv_.y)            \
    WU_SUB(4 * (Q) + 2, WC, rv_.z) WU_SUB(4 * (Q) + 3, WD, rv_.w) }
#define WU128M(W, U, RBP) { const float* rbp_ = (RBP);                       \
    const float* ALGp_ = scr + lane * 4;                                     \
    float ww0_ = 0.f, ww1_ = 0.f, ww2_ = 0.f, ww3_ = 0.f;                    \
    float uu0_ = 0.f, uu1_ = 0.f, uu2_ = 0.f, uu3_ = 0.f;                    \
    REPQ(WU_B) (W)[0] = ww0_; (W)[1] = ww1_; (W)[2] = ww2_; (W)[3] = ww3_;   \
    (U)[0] = uu0_; (U)[1] = uu1_; (U)[2] = uu2_; (U)[3] = uu3_; }

// two parents share the ALG read stream
#define WUX2_SUB(ROW, WX, RC0, RC1) {                                        \
    const float4 av_ = *(const float4*)(ALGp_ + (ROW) * 128);                \
    wa0_ = fmaf(WX.x, RC0, wa0_); wb0_ = fmaf(WX.x, RC1, wb0_);              \
    ua0_ = fmaf(av_.x, RC0, ua0_); ub0_ = fmaf(av_.x, RC1, ub0_);            \
    wa1_ = fmaf(WX.y, RC0, wa1_); wb1_ = fmaf(WX.y, RC1, wb1_);              \
    ua1_ = fmaf(av_.y, RC0, ua1_); ub1_ = fmaf(av_.y, RC1, ub1_);            \
    wa2_ = fmaf(WX.z, RC0, wa2_); wb2_ = fmaf(WX.z, RC1, wb2_);              \
    ua2_ = fmaf(av_.z, RC0, ua2_); ub2_ = fmaf(av_.z, RC1, ub2_);            \
    wa3_ = fmaf(WX.w, RC0, wa3_); wb3_ = fmaf(WX.w, RC1, wb3_);              \
    ua3_ = fmaf(av_.w, RC0, ua3_); ub3_ = fmaf(av_.w, RC1, ub3_); }
#define WUX2_B(Q, WA, WB, WC, WD) {                                          \
    const float4 rv0_ = *(const float4*)(rbp0_ + 4 * (Q));                   \
    const float4 rv1_ = *(const float4*)(rbp1_ + 4 * (Q));                   \
    WUX2_SUB(4 * (Q) + 0, WA, rv0_.x, rv1_.x)                                \
    WUX2_SUB(4 * (Q) + 1, WB, rv0_.y, rv1_.y)                                \
    WUX2_SUB(4 * (Q) + 2, WC, rv0_.z, rv1_.z)                                \
    WUX2_SUB(4 * (Q) + 3, WD, rv0_.w, rv1_.w) }
#define WU128X2M(W0, U0, W1, U1, RBP0, RBP1) {                               \
    const float* rbp0_ = (RBP0); const float* rbp1_ = (RBP1);                \
    const float* ALGp_ = scr + lane * 4;                                     \
    float wa0_ = 0.f, wa1_ = 0.f, wa2_ = 0.f, wa3_ = 0.f;                    \
    float ua0_ = 0.f, ua1_ = 0.f, ua2_ = 0.f, ua3_ = 0.f;                    \
    float wb0_ = 0.f, wb1_ = 0.f, wb2_ = 0.f, wb3_ = 0.f;                    \
    float ub0_ = 0.f, ub1_ = 0.f, ub2_ = 0.f, ub3_ = 0.f;                    \
    REPQ(WUX2_B)                                                             \
    (W0)[0] = wa0_; (W0)[1] = wa1_; (W0)[2] = wa2_; (W0)[3] = wa3_;          \
    (U0)[0] = ua0_; (U0)[1] = ua1_; (U0)[2] = ua2_; (U0)[3] = ua3_;          \
    (W1)[0] = wb0_; (W1)[1] = wb1_; (W1)[2] = wb2_; (W1)[3] = wb3_;          \
    (U1)[0] = ub0_; (U1)[1] = ub1_; (U1)[2] = ub2_; (U1)[3] = ub3_; }

// phase-4 rebuild (FALLBACK k_down only): W -> down orient; ALG into scr
#define WRD_B(J, WJ) { const float4 av = A4[(J) * 32 + lane];                \
    const float4 e = exp4f(av);                                              \
    const float4 asp = make_float4(e.x * inv4.x, e.y * inv4.y,               \
                                   e.z * inv4.z, e.w * inv4.w);              \
    WJ = asp;                                                                \
    if (grp == ((J) >> 1))                                                   \
      *(float4*)(scr + (J) * 128 + lane * 4) =                               \
          make_float4(asp.x * (av.x - sub4.x), asp.y * (av.y - sub4.y),      \
                      asp.z * (av.z - sub4.z), asp.w * (av.w - sub4.w)); }

// ======================================================================
// ===================== FALLBACK PATH (R18, proven) ====================
// ======================================================================
__global__ __launch_bounds__(256, 1) void k_up_f(const int* __restrict__ labels,
                                                 const float* __restrict__ A,
                                                 const float* __restrict__ B,
                                                 const float* __restrict__ Pi,
                                                 const float* __restrict__ SP,
                                                 float* __restrict__ ws) {
  __shared__ __align__(16) float scr[4224];
  __shared__ __align__(16) float regB[4224];
  __shared__ __align__(16) float sPt[132];
  __shared__ int labs[425];
  const int t = threadIdx.x, lane = t & 31, grp = t >> 5;
  const int s = blockIdx.x;
  int* wsi = (int*)ws;
  const float4* A4 = (const float4*)A;
  const float4* B4 = (const float4*)B;

  if (t < 16) wsi[IC2 + 32 * t] = 0;
  else if (t == 16) wsi[IROOT2] = 0;

  const float sv0 = SP[0], sv1 = SP[1], sv2 = SP[2], sv3 = SP[3];
  const float sp0 = __expf(sv0), sp1 = __expf(sv1), sp2 = __expf(sv2), sp3 = __expf(sv3);
  const float spsum = sp0 + sp1 + sp2 + sp3;
  const float spinv = 1.f / spsum;
  float4 c4 = make_float4(0.f, 0.f, 0.f, 0.f);
  for (int i = 0; i < 32; ++i) {
    const float4 e = exp4f(A4[i * 32 + lane]);
    c4.x += e.x; c4.y += e.y; c4.z += e.z; c4.w += e.w;
  }
  const float4 inv4 = make_float4(sp0 * spinv / c4.x, sp1 * spinv / c4.y,
                                  sp2 * spinv / c4.z, sp3 * spinv / c4.w);
#pragma unroll
  for (int k = 0; k < 4; ++k) {
    const int i = grp * 4 + k;
    const float4 e = exp4f(A4[i * 32 + lane]);
    *(float4*)(scr + i * 132 + 4 * lane) =
        make_float4(e.x * inv4.x, e.y * inv4.y, e.z * inv4.z, e.w * inv4.w);
  }
#pragma unroll
  for (int rI = 0; rI < 4; ++rI) {
    const int i = grp + rI * 8;
    const float4 e = exp4f(B4[i * 32 + lane]);
    const float sinv = 1.f / rsum32(e.x + e.y + e.z + e.w);
    regB[(4 * lane + 0) * 33 + i] = e.x * sinv;
    regB[(4 * lane + 1) * 33 + i] = e.y * sinv;
    regB[(4 * lane + 2) * 33 + i] = e.z * sinv;
    regB[(4 * lane + 3) * 33 + i] = e.w * sinv;
  }
  if (grp < 4) {
    const float e = __expf(Pi[lane * 4 + grp]);
    sPt[grp * 33 + lane] = e / rsum32(e);
  }
  if (t < 84) {
    int g, d;
    if (t < 4) { g = 341 + 4 * s + t; d = 341 + t; }
    else if (t < 20) { g = 1365 + 16 * s + (t - 4); d = 345 + (t - 4); }
    else { g = 5461 + 64 * s + (t - 20); d = 361 + (t - 20); }
    labs[d] = labels[g];
  }
  if (t == 84) labs[85 + (s & 255)] = labels[85 + s];
  __syncthreads();
  W_DECL
  W_LOADUP
  __syncthreads();

#pragma unroll
  for (int h = 0; h < 2; ++h) {
    const int q0 = grp + 32 * h, q1 = q0 + 8, q2 = q0 + 16, q3 = q0 + 24;
    float v0 = sPt[(q0 & 3) * 33 + lane] * regB[labs[361 + q0] * 33 + lane];
    float v1 = sPt[(q1 & 3) * 33 + lane] * regB[labs[361 + q1] * 33 + lane];
    float v2 = sPt[(q2 & 3) * 33 + lane] * regB[labs[361 + q2] * 33 + lane];
    float v3 = sPt[(q3 & 3) * 33 + lane] * regB[labs[361 + q3] * 33 + lane];
    float s0 = v0, s1 = v1, s2 = v2, s3 = v3;
    rsum32x4(s0, s1, s2, s3);
    scr[(q0 >> 2) * 128 + lane * 4 + (q0 & 3)] = v0 / s0;
    scr[(q1 >> 2) * 128 + lane * 4 + (q1 & 3)] = v1 / s1;
    scr[(q2 >> 2) * 128 + lane * 4 + (q2 & 3)] = v2 / s2;
    scr[(q3 >> 2) * 128 + lane * 4 + (q3 & 3)] = v3 / s3;
  }
  __syncthreads();
  {
    const int p0 = grp, p1 = grp + 8;
    float tb0, tb1;
    DOT128X2M(tb0, tb1, scr + p0 * 128, scr + p1 * 128)
    float bl0 = tb0 * regB[labs[345 + p0] * 33 + lane];
    float bl1 = tb1 * regB[labs[345 + p1] * 33 + lane];
    float s0 = bl0, s1 = bl1;
    rsum32x2(s0, s1);
    bl0 /= s0; bl1 /= s1;
    scr[2048 + (p0 >> 2) * 128 + lane * 4 + (p0 & 3)] = bl0;
    scr[2048 + (p1 >> 2) * 128 + lane * 4 + (p1 & 3)] = bl1;
  }
  __syncthreads();
  if (grp < 4) {
    float tb;
    DOT128M(tb, scr + 2048 + grp * 128)
    float bl = tb * regB[labs[341 + grp] * 33 + lane];
    bl /= rsum32(bl);
    scr[2560 + lane * 4 + grp] = bl;
  }
  __syncthreads();
  if (grp == 0) {
    float tb;
    DOT128M(tb, scr + 2560)
    float bl = tb * regB[labs[85 + (s & 255)] * 33 + lane];
    bl /= rsum32(bl);
    ws[OFF_B4 + s * 32 + lane] = bl;
  }
}

__global__ __launch_bounds__(512, 1)
void k_down_f(const int* __restrict__ labels,
              const float* __restrict__ A,
              const float* __restrict__ B,
              const float* __restrict__ Pi,
              const float* __restrict__ SP,
              float* __restrict__ ws,
              float* __restrict__ out) {
  __shared__ __align__(16) float scr[6144];
  __shared__ __align__(16) float regB[4224];
  __shared__ __align__(16) float sPt[132];
  __shared__ __align__(16) float tbrT[2720];
  __shared__ __align__(16) float tbS[672];
  __shared__ __align__(16) float ownb[32];
  __shared__ __align__(16) float r_buf[512];
  __shared__ int labs[425];
  __shared__ int fin;
  const int t = threadIdx.x, lane = t & 31, grp = t >> 5;
  const int s = blockIdx.x;
  int* wsi = (int*)ws;
  double* partd = (double*)(ws + OFF_PART);
  const float4* A4 = (const float4*)A;
  const float4* B4 = (const float4*)B;

  float pf0[8], pf1[8];
#pragma unroll
  for (int h = 0; h < 2; ++h) {
    const int p0 = grp + 32 * h, p1 = p0 + 16;
#pragma unroll
    for (int l = 0; l < 4; ++l) {
      pf0[h * 4 + l] = ws[OFF_B4 + (p0 * 4 + l) * 32 + lane];
      pf1[h * 4 + l] = ws[OFF_B4 + (p1 * 4 + l) * 32 + lane];
    }
  }

  const float sv0 = SP[0], sv1 = SP[1], sv2 = SP[2], sv3 = SP[3];
  const float sp0 = __expf(sv0), sp1 = __expf(sv1), sp2 = __expf(sv2), sp3 = __expf(sv3);
  const float spsum = sp0 + sp1 + sp2 + sp3;
  const float spinv = 1.f / spsum;
  const float lss = __logf(spsum);
  float4 c4 = make_float4(0.f, 0.f, 0.f, 0.f);
  for (int i = 0; i < 32; ++i) {
    const float4 e = exp4f(A4[i * 32 + lane]);
    c4.x += e.x; c4.y += e.y; c4.z += e.z; c4.w += e.w;
  }
  const float4 inv4 = make_float4(sp0 * spinv / c4.x, sp1 * spinv / c4.y,
                                  sp2 * spinv / c4.z, sp3 * spinv / c4.w);
  const float4 sub4 = make_float4(__logf(c4.x) - (sv0 - lss), __logf(c4.y) - (sv1 - lss),
                                  __logf(c4.z) - (sv2 - lss), __logf(c4.w) - (sv3 - lss));
#pragma unroll
  for (int k = 0; k < 2; ++k) {
    const int i = grp * 2 + k;
    const float4 e = exp4f(A4[i * 32 + lane]);
    *(float4*)(scr + i * 132 + 4 * lane) =
        make_float4(e.x * inv4.x, e.y * inv4.y, e.z * inv4.z, e.w * inv4.w);
  }
#pragma unroll
  for (int rI = 0; rI < 2; ++rI) {
    const int i = grp + rI * 16;
    const float4 e = exp4f(B4[i * 32 + lane]);
    const float sinv = 1.f / rsum32(e.x + e.y + e.z + e.w);
    regB[(4 * lane + 0) * 33 + i] = e.x * sinv;
    regB[(4 * lane + 1) * 33 + i] = e.y * sinv;
    regB[(4 * lane + 2) * 33 + i] = e.z * sinv;
    regB[(4 * lane + 3) * 33 + i] = e.w * sinv;
  }
  if (grp < 4) {
    const float e = __expf(Pi[lane * 4 + grp]);
    sPt[grp * 33 + lane] = e / rsum32(e);
  }
  for (int idx = t; idx < 341; idx += 512) labs[idx] = labels[idx];
  if (t < 84) {
    int g, d;
    if (t < 4) { g = 341 + 4 * s + t; d = 341 + t; }
    else if (t < 20) { g = 1365 + 16 * s + (t - 4); d = 345 + (t - 4); }
    else { g = 5461 + 64 * s + (t - 20); d = 361 + (t - 20); }
    labs[d] = labels[g];
  }
  __syncthreads();
  W_DECL
  W_LOADUP
  __syncthreads();

  {
    const int q0 = grp, q1 = grp + 16, q2 = grp + 32, q3 = grp + 48;
    float v0 = sPt[(q0 & 3) * 33 + lane] * regB[labs[361 + q0] * 33 + lane];
    float v1 = sPt[(q1 & 3) * 33 + lane] * regB[labs[361 + q1] * 33 + lane];
    float v2 = sPt[(q2 & 3) * 33 + lane] * regB[labs[361 + q2] * 33 + lane];
    float v3 = sPt[(q3 & 3) * 33 + lane] * regB[labs[361 + q3] * 33 + lane];
    float s0 = v0, s1 = v1, s2 = v2, s3 = v3;
    rsum32x4(s0, s1, s2, s3);
    scr[(q0 >> 2) * 128 + lane * 4 + (q0 & 3)] = v0 / s0;
    scr[(q1 >> 2) * 128 + lane * 4 + (q1 & 3)] = v1 / s1;
    scr[(q2 >> 2) * 128 + lane * 4 + (q2 & 3)] = v2 / s2;
    scr[(q3 >> 2) * 128 + lane * 4 + (q3 & 3)] = v3 / s3;
  }
  __syncthreads();
  if (grp < 8) {
    const int p0 = grp, p1 = grp + 8;
    float tb0, tb1;
    DOT128X2M(tb0, tb1, scr + p0 * 128, scr + p1 * 128)
    float bl0 = tb0 * regB[labs[345 + p0] * 33 + lane];
    float bl1 = tb1 * regB[labs[345 + p1] * 33 + lane];
    float s0 = bl0, s1 = bl1;
    rsum32x2(s0, s1);
    bl0 /= s0; bl1 /= s1;
    tbS[(5 + p0) * 32 + lane] = tb0;
    tbS[(5 + p1) * 32 + lane] = tb1;
    scr[2048 + (p0 >> 2) * 128 + lane * 4 + (p0 & 3)] = bl0;
    scr[2048 + (p1 >> 2) * 128 + lane * 4 + (p1 & 3)] = bl1;
  }
  __syncthreads();
  if (grp < 4) {
    float tb;
    DOT128M(tb, scr + 2048 + grp * 128)
    float bl = tb * regB[labs[341 + grp] * 33 + lane];
    bl /= rsum32(bl);
    tbS[(1 + grp) * 32 + lane] = tb;
    scr[2560 + lane * 4 + grp] = bl;
  }
  __syncthreads();
  if (grp == 0) {
    float tb;
    DOT128M(tb, scr + 2560)
    float bl = tb * regB[labs[85 + s] * 33 + lane];
    bl /= rsum32(bl);
    tbS[lane] = tb;
    ownb[lane] = bl;
  }
  __syncthreads();

#pragma unroll
  for (int h = 0; h < 2; ++h) {
    const int p0 = grp + 32 * h, p1 = p0 + 16;
    float* st0 = scr + grp * 128;
    float* st1 = scr + 2048 + grp * 128;
#pragma unroll
    for (int l = 0; l < 4; ++l) {
      st0[lane * 4 + l] = pf0[h * 4 + l];
      st1[lane * 4 + l] = pf1[h * 4 + l];
    }
    float tb0, tb1;
    DOT128X2M(tb0, tb1, st0, st1)
    float bl0 = tb0 * regB[labs[21 + p0] * 33 + lane];
    float bl1 = tb1 * regB[labs[21 + p1] * 33 + lane];
    float s0 = bl0, s1 = bl1;
    rsum32x2(s0, s1);
    bl0 /= s0; bl1 /= s1;
    tbrT[(21 + p0) * 32 + lane] = tb0;
    tbrT[(21 + p1) * 32 + lane] = tb1;
    scr[4096 + (p0 >> 2) * 128 + lane * 4 + (p0 & 3)] = bl0;
    scr[4096 + (p1 >> 2) * 128 + lane * 4 + (p1 & 3)] = bl1;
  }
  __syncthreads();
  {
    const int p = grp;
    float tb;
    DOT128M(tb, scr + 4096 + p * 128)
    float bl = tb * regB[labs[5 + p] * 33 + lane];
    bl /= rsum32(bl);
    tbrT[(5 + p) * 32 + lane] = tb;
    scr[(p >> 2) * 128 + lane * 4 + (p & 3)] = bl;
  }
  __syncthreads();
  if (grp < 4) {
    float tb;
    DOT128M(tb, scr + grp * 128)
    float bl = tb * regB[labs[1 + grp] * 33 + lane];
    bl /= rsum32(bl);
    tbrT[(1 + grp) * 32 + lane] = tb;
    scr[512 + lane * 4 + grp] = bl;
  }
  __syncthreads();
  if (grp == 0) { float tb; DOT128M(tb, scr + 512) tbrT[lane] = tb; }
  __syncthreads();

  for (int idx = t; idx < 4224; idx += 512) regB[idx] = __logf(regB[idx]);
  if (t < 132) sPt[t] = __logf(sPt[t]);
  REPW(WRD_B)
  __syncthreads();

  double ll = 0.0;
  float eps4own = 0.f;
  if (grp < 4) {
    const int n1 = 1 + (s >> 6), n2 = 5 + (s >> 4), n3 = 21 + (s >> 2);
    const int a0 = s >> 6, a1 = (s >> 4) & 3, a2 = (s >> 2) & 3, a3 = s & 3;
    float w[4], uv[4];
    float* rb = r_buf + grp * 32;

    float tbv = tbrT[lane];
    float bcv = tbv * __expf(regB[labs[0] * 33 + lane]);
    bcv /= rsum32(bcv);
    rb[lane] = bcv / tbv;
    if (grp == 0 && s == 0) {
      ll += (double)(bcv * regB[labs[0] * 33 + lane]);
      WU128M(w, uv, rb)
      const float lb0 = regB[labs[1] * 33 + lane], lb1 = regB[labs[2] * 33 + lane];
      const float lb2 = regB[labs[3] * 33 + lane], lb3 = regB[labs[4] * 33 + lane];
      float b0 = tbrT[1 * 32 + lane] * __expf(lb0);
      float b1 = tbrT[2 * 32 + lane] * __expf(lb1);
      float b2 = tbrT[3 * 32 + lane] * __expf(lb2);
      float b3 = tbrT[4 * 32 + lane] * __expf(lb3);
      float s0 = b0, s1 = b1, s2 = b2, s3 = b3;
      rsum32x4(s0, s1, s2, s3);
      b0 /= s0; b1 /= s1; b2 /= s2; b3 /= s3;
      ll += (double)(b0 * uv[0]) + (double)(b0 * w[0] * lb0);
      ll += (double)(b1 * uv[1]) + (double)(b1 * w[1] * lb1);
      ll += (double)(b2 * uv[2]) + (double)(b2 * w[2] * lb2);
      ll += (double)(b3 * uv[3]) + (double)(b3 * w[3] * lb3);
    } else {
      WONLY128M(w, rb)
    }

    tbv = tbrT[n1 * 32 + lane];
    bcv = tbv * __expf(regB[labs[n1] * 33 + lane]);
    bcv /= rsum32(bcv);
    rb[lane] = (bcv * w[a0]) / tbv;
    if (grp == 1 && (s & 63) == 0) {
      WU128M(w, uv, rb)
      const int cb = 5 + 4 * (s >> 6);
      const float lb0 = regB[labs[cb + 0] * 33 + lane], lb1 = regB[labs[cb + 1] * 33 + lane];
      const float lb2 = regB[labs[cb + 2] * 33 + lane], lb3 = regB[labs[cb + 3] * 33 + lane];
      float b0 = tbrT[(cb + 0) * 32 + lane] * __expf(lb0);
      float b1 = tbrT[(cb + 1) * 32 + lane] * __expf(lb1);
      float b2 = tbrT[(cb + 2) * 32 + lane] * __expf(lb2);
      float b3 = tbrT[(cb + 3) * 32 + lane] * __expf(lb3);
      float s0 = b0, s1 = b1, s2 = b2, s3 = b3;
      rsum32x4(s0, s1, s2, s3);
      b0 /= s0; b1 /= s1; b2 /= s2; b3 /= s3;
      ll += (double)(b0 * uv[0]) + (double)(b0 * w[0] * lb0);
      ll += (double)(b1 * uv[1]) + (double)(b1 * w[1] * lb1);
      ll += (double)(b2 * uv[2]) + (double)(b2 * w[2] * lb2);
      ll += (double)(b3 * uv[3]) + (double)(b3 * w[3] * lb3);
    } else {
      WONLY128M(w, rb)
    }

    tbv = tbrT[n2 * 32 + lane];
    bcv = tbv * __expf(regB[labs[n2] * 33 + lane]);
    bcv /= rsum32(bcv);
    rb[lane] = (bcv * w[a1]) / tbv;
    if (grp == 2 && (s & 15) == 0) {
      WU128M(w, uv, rb)
      const int cb = 21 + 4 * (s >> 4);
      const float lb0 = regB[labs[cb + 0] * 33 + lane], lb1 = regB[labs[cb + 1] * 33 + lane];
      const float lb2 = regB[labs[cb + 2] * 33 + lane], lb3 = regB[labs[cb + 3] * 33 + lane];
      float b0 = tbrT[(cb + 0) * 32 + lane] * __expf(lb0);
      float b1 = tbrT[(cb + 1) * 32 + lane] * __expf(lb1);
      float b2 = tbrT[(cb + 2) * 32 + lane] * __expf(lb2);
      float b3 = tbrT[(cb + 3) * 32 + lane] * __expf(lb3);
      float s0 = b0, s1 = b1, s2 = b2, s3 = b3;
      rsum32x4(s0, s1, s2, s3);
      b0 /= s0; b1 /= s1; b2 /= s2; b3 /= s3;
      ll += (double)(b0 * uv[0]) + (double)(b0 * w[0] * lb0);
      ll += (double)(b1 * uv[1]) + (double)(b1 * w[1] * lb1);
      ll += (double)(b2 * uv[2]) + (double)(b2 * w[2] * lb2);
      ll += (double)(b3 * uv[3]) + (double)(b3 * w[3] * lb3);
    } else {
      WONLY128M(w, rb)
    }

    tbv = tbrT[n3 * 32 + lane];
    bcv = tbv * __expf(regB[labs[n3] * 33 + lane]);
    bcv /= rsum32(bcv);
    rb[lane] = (bcv * w[a2]) / tbv;
    if (grp == 3 && (s & 3) == 0) {
      WU128M(w, uv, rb)
      const int cb = s & ~3;
#pragma unroll
      for (int l = 0; l < 4; ++l) {
        const int ci = cb + l;
        const float bc = ws[OFF_B4 + ci * 32 + lane];
        const float e = bc * w[l];
        ll += (double)(bc * uv[l]) + (double)(e * regB[labs[85 + ci] * 33 + lane]);
      }
    } else {
      WONLY128M(w, rb)
    }
    eps4own = ownb[lane] * w[a3];
  }
  __syncthreads();

  if (grp == 0) {
    r_buf[lane] = eps4own / tbS[lane];
    float w[4], u[4];
    WU128M(w, u, r_buf)
#pragma unroll
    for (int l = 0; l < 4; ++l) {
      const int lab = labs[341 + l];
      const float tbv = tbS[(1 + l) * 32 + lane];
      float bcv = tbv * __expf(regB[lab * 33 + lane]);
      bcv /= rsum32(bcv);
      const float e = bcv * w[l];
      ll += (double)(bcv * u[l]) + (double)(e * regB[lab * 33 + lane]);
      tbS[(1 + l) * 32 + lane] = e / tbv;
    }
  }
  __syncthreads();
  if (grp < 4) {
    const int p = grp;
    r_buf[p * 32 + lane] = tbS[(1 + p) * 32 + lane];
    float w[4], u[4];
    WU128M(w, u, r_buf + p * 32)
#pragma unroll
    for (int l = 0; l < 4; ++l) {
      const int q = p * 4 + l;
      const int lab = labs[345 + q];
      const float tbv = tbS[(5 + q) * 32 + lane];
      float bcv = tbv * __expf(regB[lab * 33 + lane]);
      bcv /= rsum32(bcv);
      const float e = bcv * w[l];
      ll += (double)(bcv * u[l]) + (double)(e * regB[lab * 33 + lane]);
      tbS[(5 + q) * 32 + lane] = e / tbv;
    }
  }
  __syncthreads();
  if (grp < 8) {
    const int p0 = grp, p1 = grp + 8;
    float* rb0 = r_buf + grp * 32;
    float* rb1 = r_buf + 256 + grp * 32;
    rb0[lane] = tbS[(5 + p0) * 32 + lane];
    rb1[lane] = tbS[(5 + p1) * 32 + lane];
    float w0[4], u0[4], w1[4], u1[4];
    WU128X2M(w0, u0, w1, u1, rb0, rb1)
#pragma unroll
    for (int l = 0; l < 4; ++l) {
      const int q0 = p0 * 4 + l, q1 = p1 * 4 + l;
      const float lb0 = regB[labs[361 + q0] * 33 + lane];
      const float lb1 = regB[labs[361 + q1] * 33 + lane];
      const float lp = sPt[l * 33 + lane];
      float b0 = __expf(lp + lb0);
      float b1 = __expf(lp + lb1);
      float s0 = b0, s1 = b1;
      rsum32x2(s0, s1);
      b0 /= s0; b1 /= s1;
      const float e0 = b0 * w0[l], e1 = b1 * w1[l];
      ll += (double)(b0 * u0[l]) + (double)(e0 * lb0) + (double)(e0 * lp);
      ll += (double)(b1 * u1[l]) + (double)(e1 * lb1) + (double)(e1 * lp);
    }
  }

#pragma unroll
  for (int k = 32; k >= 1; k >>= 1) ll += __shfl_xor(ll, k);
  double* rbd = (double*)r_buf;
  __syncthreads();
  if ((t & 63) == 0) rbd[t >> 6] = ll;
  __syncthreads();
  if (t == 0) {
    partd[s] = ((rbd[0] + rbd[1]) + (rbd[2] + rbd[3])) +
               ((rbd[4] + rbd[5]) + (rbd[6] + rbd[7]));
    __threadfence();
    int f = 0;
    if (atomicAdd(&wsi[IC2 + 32 * (s >> 4)], 1) == 15)
      if (atomicAdd(&wsi[IROOT2], 1) == 15) f = 1;
    fin = f;
  }
  __syncthreads();
  if (fin) {
    __threadfence();
    if (t < 64) {
      double v = 0.0;
      for (int k = t; k < 256; k += 64) v += partd[k];
#pragma unroll
      for (int k = 32; k >= 1; k >>= 1) v += __shfl_xor(v, k);
      if (t == 0) out[0] = (float)v;
    }
  }
}

// ======================================================================
// ================= PERSIST PATH (R22 design + R23 cuts) ===============
// ======================================================================
__global__ __launch_bounds__(512, 1) void k_up_p(const int* __restrict__ labels,
                                                 const float* __restrict__ A,
                                                 const float* __restrict__ B,
                                                 const float* __restrict__ Pi,
                                                 const float* __restrict__ SP,
                                                 float* __restrict__ ws) {
  __shared__ __align__(16) float scr[4224];
  __shared__ __align__(16) float regB[4224];
  __shared__ __align__(16) float sPt[132];
  __shared__ int labs[425];
  const int t = threadIdx.x, lane = t & 31, grp = t >> 5;  // 16 groups
  const int s = blockIdx.x;
  int* wsi = (int*)ws;
  const float4* A4 = (const float4*)A;
  const float4* B4 = (const float4*)B;

  if (t < 16) wsi[IC2 + 32 * t] = 0;
  else if (t == 16) wsi[IROOT2] = 0;

  const float sv0 = SP[0], sv1 = SP[1], sv2 = SP[2], sv3 = SP[3];
  const float sp0 = __expf(sv0), sp1 = __expf(sv1), sp2 = __expf(sv2), sp3 = __expf(sv3);
  const float spsum = sp0 + sp1 + sp2 + sp3;
  const float spinv = 1.f / spsum;
  const float lss = __logf(spsum);
  float4 c4 = make_float4(0.f, 0.f, 0.f, 0.f);
  for (int i = 0; i < 32; ++i) {
    const float4 e = exp4f(A4[i * 32 + lane]);
    c4.x += e.x; c4.y += e.y; c4.z += e.z; c4.w += e.w;
  }
  const float4 inv4 = make_float4(sp0 * spinv / c4.x, sp1 * spinv / c4.y,
                                  sp2 * spinv / c4.z, sp3 * spinv / c4.w);
  const float4 sub4 = make_float4(__logf(c4.x) - (sv0 - lss), __logf(c4.y) - (sv1 - lss),
                                  __logf(c4.z) - (sv2 - lss), __logf(c4.w) - (sv3 - lss));
#pragma unroll
  for (int k = 0; k < 2; ++k) {
    const int i = grp * 2 + k;
    const float4 e = exp4f(A4[i * 32 + lane]);
    *(float4*)(scr + i * 132 + 4 * lane) =
        make_float4(e.x * inv4.x, e.y * inv4.y, e.z * inv4.z, e.w * inv4.w);
  }
#pragma unroll
  for (int rI = 0; rI < 2; ++rI) {
    const int i = grp + rI * 16;
    const float4 e = exp4f(B4[i * 32 + lane]);
    const float sinv = 1.f / rsum32(e.x + e.y + e.z + e.w);
    regB[(4 * lane + 0) * 33 + i] = e.x * sinv;
    regB[(4 * lane + 1) * 33 + i] = e.y * sinv;
    regB[(4 * lane + 2) * 33 + i] = e.z * sinv;
    regB[(4 * lane + 3) * 33 + i] = e.w * sinv;
  }
  if (grp < 4) {
    const float e = __expf(Pi[lane * 4 + grp]);
    sPt[grp * 33 + lane] = e / rsum32(e);
  } else if (grp == 4) {  // fill the 4 gap slots so persisted logs are finite
    if (lane < 4) sPt[lane * 33 + 32] = 1.f;
  }
  if (t < 84) {
    int g, d;
    if (t < 4) { g = 341 + 4 * s + t; d = 341 + t; }
    else if (t < 20) { g = 1365 + 16 * s + (t - 4); d = 345 + (t - 4); }
    else { g = 5461 + 64 * s + (t - 20); d = 361 + (t - 20); }
    labs[d] = labels[g];
  }
  if (t == 84) labs[85 + (s & 255)] = labels[85 + s];
  __syncthreads();

  // ---------- block 0: persist block-independent tables ----------
  if (s == 0) {
    for (int idx = t; idx < 4224; idx += 512) {
      ws[OFF_ASP + idx] = scr[idx];
      const float v = regB[idx];
      ws[OFF_RB + idx] = v;
      ws[OFF_LRB + idx] = __logf(v);
    }
    if (t < 132) ws[OFF_LSP + t] = __logf(sPt[t]);
#pragma unroll
    for (int k = 0; k < 2; ++k) {
      const int i = grp * 2 + k;
      const float4 av = A4[i * 32 + lane];
      const float4 e = exp4f(av);
      const float4 asp = make_float4(e.x * inv4.x, e.y * inv4.y,
                                     e.z * inv4.z, e.w * inv4.w);
      *(float4*)(ws + OFF_ALG + i * 128 + lane * 4) =
          make_float4(asp.x * (av.x - sub4.x), asp.y * (av.y - sub4.y),
                      asp.z * (av.z - sub4.z), asp.w * (av.w - sub4.w));
    }
  }
  W_DECL
  W_LOADUP
  __syncthreads();

  // ---------- phase 2: subtree up sweep; persist tbS rows + b4 ----------
  float* tbs = ws + OFF_TBO + s * 672;
  {
    const int q0 = grp, q1 = grp + 16, q2 = grp + 32, q3 = grp + 48;
    float v0 = sPt[(q0 & 3) * 33 + lane] * regB[labs[361 + q0] * 33 + lane];
    float v1 = sPt[(q1 & 3) * 33 + lane] * regB[labs[361 + q1] * 33 + lane];
    float v2 = sPt[(q2 & 3) * 33 + lane] * regB[labs[361 + q2] * 33 + lane];
    float v3 = sPt[(q3 & 3) * 33 + lane] * regB[labs[361 + q3] * 33 + lane];
    float s0 = v0, s1 = v1, s2 = v2, s3 = v3;
    rsum32x4(s0, s1, s2, s3);
    scr[(q0 >> 2) * 128 + lane * 4 + (q0 & 3)] = v0 / s0;
    scr[(q1 >> 2) * 128 + lane * 4 + (q1 & 3)] = v1 / s1;
    scr[(q2 >> 2) * 128 + lane * 4 + (q2 & 3)] = v2 / s2;
    scr[(q3 >> 2) * 128 + lane * 4 + (q3 & 3)] = v3 / s3;
  }
  __syncthreads();
  {  // S2: 16 L6 parents, ONE per group
    const int p = grp;
    float tb;
    DOT128M(tb, scr + p * 128)
    float bl = tb * regB[labs[345 + p] * 33 + lane];
    bl /= rsum32(bl);
    tbs[(5 + p) * 32 + lane] = tb;
    scr[2048 + (p >> 2) * 128 + lane * 4 + (p & 3)] = bl;  // X6
  }
  __syncthreads();
  if (grp < 4) {
    float tb;
    DOT128M(tb, scr + 2048 + grp * 128)
    float bl = tb * regB[labs[341 + grp] * 33 + lane];
    bl /= rsum32(bl);
    tbs[(1 + grp) * 32 + lane] = tb;
    scr[2560 + lane * 4 + grp] = bl;
  }
  __syncthreads();
  if (grp == 0) {
    float tb;
    DOT128M(tb, scr + 2560)
    float bl = tb * regB[labs[85 + (s & 255)] * 33 + lane];
    bl /= rsum32(bl);
    tbs[lane] = tb;
    ws[OFF_B4 + s * 32 + lane] = bl;
  }
}

__global__ __launch_bounds__(512, 1)
void k_down_p(const int* __restrict__ labels,
              const float* __restrict__ ws_c,
              float* __restrict__ ws,
              float* __restrict__ out) {
  __shared__ __align__(16) float scr[10880];   // 85 rows: P3 staging + bX*
  __shared__ __align__(16) float aspL[4224];   // R23: permanent asp copy
  __shared__ __align__(16) float logBL[4224];  // R23: logB home (regB=smB)
  __shared__ __align__(16) float regB[4224];
  __shared__ __align__(16) float sPt[132];
  __shared__ __align__(16) float tbrT[2720];
  __shared__ __align__(16) float tbS[672];
  __shared__ __align__(16) float ownb[32];
  __shared__ __align__(16) float r_buf[512];
  __shared__ int labs[425];
  __shared__ int fin;
  const int t = threadIdx.x, lane = t & 31, grp = t >> 5;  // 16 groups
  const int s = blockIdx.x;
  int* wsi = (int*)ws;
  double* partd = (double*)(ws + OFF_PART);
  (void)ws_c;

  // ---------- early prefetch: P3's b4 children ----------
  float pf0[8], pf1[8];
#pragma unroll
  for (int h = 0; h < 2; ++h) {
    const int p0 = grp + 32 * h, p1 = p0 + 16;
#pragma unroll
    for (int l = 0; l < 4; ++l) {
      pf0[h * 4 + l] = ws[OFF_B4 + (p0 * 4 + l) * 32 + lane];
      pf1[h * 4 + l] = ws[OFF_B4 + (p1 * 4 + l) * 32 + lane];
    }
  }
  // ---------- early prefetch: ALG + logB tables into regs ----------
  const float4* wsALG4 = (const float4*)(ws + OFF_ALG);   // 1024 float4
  const float4* wsLRB4 = (const float4*)(ws + OFF_LRB);   // 1056 float4
  float4 pfA0 = wsALG4[t];
  float4 pfA1 = wsALG4[t + 512];
  float4 pfL0 = wsLRB4[t];
  float4 pfL1 = wsLRB4[t + 512];
  float4 pfL2 = make_float4(0.f, 0.f, 0.f, 0.f);
  if (t < 32) pfL2 = wsLRB4[t + 1024];

  // ---------- stage tables + per-block state from ws (float4) ----------
  {
    const float4* wsASP4 = (const float4*)(ws + OFF_ASP);  // 1056 float4
    const float4* wsRB4 = (const float4*)(ws + OFF_RB);    // 1056 float4
    float4* aspL4 = (float4*)aspL;
    float4* regB4 = (float4*)regB;
    aspL4[t] = wsASP4[t];
    aspL4[t + 512] = wsASP4[t + 512];
    regB4[t] = wsRB4[t];
    regB4[t + 512] = wsRB4[t + 512];
    if (t < 32) {
      aspL4[t + 1024] = wsASP4[t + 1024];
      regB4[t + 1024] = wsRB4[t + 1024];
    }
    if (t < 33) ((float4*)sPt)[t] = ((const float4*)(ws + OFF_LSP))[t];
    if (t < 168) ((float4*)tbS)[t] = ((const float4*)(ws + OFF_TBO + s * 672))[t];
    if (t < 8) ((float4*)ownb)[t] = ((const float4*)(ws + OFF_B4 + s * 32))[t];
  }
  for (int idx = t; idx < 341; idx += 512) labs[idx] = labels[idx];
  if (t < 84) {
    int g, d;
    if (t < 4) { g = 341 + 4 * s + t; d = 341 + t; }
    else if (t < 20) { g = 1365 + 16 * s + (t - 4); d = 345 + (t - 4); }
    else { g = 5461 + 64 * s + (t - 20); d = 361 + (t - 20); }
    labs[d] = labels[g];
  }
  __syncthreads();
  W_DECL
  W_LOADUPA
  __syncthreads();

  // ---------- phase 3: top up sweep (rounds de-serialized) ----------
  // Staging rows 0..63 (scr[0..8191]); bX3 rows 64..79 (scr[8192..10239]).
  {
#pragma unroll
    for (int h = 0; h < 2; ++h) {
      float* st0 = scr + h * 4096 + grp * 128;
      float* st1 = scr + h * 4096 + 2048 + grp * 128;
#pragma unroll
      for (int l = 0; l < 4; ++l) {
        st0[lane * 4 + l] = pf0[h * 4 + l];
        st1[lane * 4 + l] = pf1[h * 4 + l];
      }
    }
    const int pA0 = grp, pA1 = grp + 16, pB0 = grp + 32, pB1 = grp + 48;
    float tbA0, tbA1, tbB0, tbB1;
    DOT128X2M(tbA0, tbA1, scr + grp * 128, scr + 2048 + grp * 128)
    DOT128X2M(tbB0, tbB1, scr + 4096 + grp * 128, scr + 4096 + 2048 + grp * 128)
    float blA0 = tbA0 * regB[labs[21 + pA0] * 33 + lane];
    float blA1 = tbA1 * regB[labs[21 + pA1] * 33 + lane];
    float blB0 = tbB0 * regB[labs[21 + pB0] * 33 + lane];
    float blB1 = tbB1 * regB[labs[21 + pB1] * 33 + lane];
    float sA0 = blA0, sA1 = blA1, sB0 = blB0, sB1 = blB1;
    rsum32x4(sA0, sA1, sB0, sB1);
    blA0 /= sA0; blA1 /= sA1; blB0 /= sB0; blB1 /= sB1;
    tbrT[(21 + pA0) * 32 + lane] = tbA0;
    tbrT[(21 + pA1) * 32 + lane] = tbA1;
    tbrT[(21 + pB0) * 32 + lane] = tbB0;
    tbrT[(21 + pB1) * 32 + lane] = tbB1;
    scr[8192 + (pA0 >> 2) * 128 + lane * 4 + (pA0 & 3)] = blA0;  // bX3
    scr[8192 + (pA1 >> 2) * 128 + lane * 4 + (pA1 & 3)] = blA1;
    scr[8192 + (pB0 >> 2) * 128 + lane * 4 + (pB0 & 3)] = blB0;
    scr[8192 + (pB1 >> 2) * 128 + lane * 4 + (pB1 & 3)] = blB1;
  }
  __syncthreads();
  {  // L2 phase; ALSO write ALG (scr rows 0..31, dead) + logBL early (R23)
    ((float4*)scr)[t] = pfA0;
    ((float4*)scr)[t + 512] = pfA1;
    ((float4*)logBL)[t] = pfL0;
    ((float4*)logBL)[t + 512] = pfL1;
    if (t < 32) ((float4*)logBL)[t + 1024] = pfL2;
    const int p = grp;
    float tb;
    DOT128M(tb, scr + 8192 + p * 128)
    float bl = tb * regB[labs[5 + p] * 33 + lane];
    bl /= rsum32(bl);
    tbrT[(5 + p) * 32 + lane] = tb;
    scr[10240 + (p >> 2) * 128 + lane * 4 + (p & 3)] = bl;  // bX2 rows 80-83
  }
  __syncthreads();
  if (grp < 4) {  // L1: 4 parents
    float tb;
    DOT128M(tb, scr + 10240 + grp * 128)
    float bl = tb * regB[labs[1 + grp] * 33 + lane];
    bl /= rsum32(bl);
    tbrT[(1 + grp) * 32 + lane] = tb;
    scr[10752 + lane * 4 + grp] = bl;  // bX1 (row 84)
  }
  __syncthreads();
  if (grp == 0) { float tb; DOT128M(tb, scr + 10752) tbrT[lane] = tb; }
  __syncthreads();

  // ---------- phase 4 (slim): reload W in down-orient from aspL (LDS) ----
  if (grp < 8) {
    const float* wsASP_ = aspL;
    REPW(WLDDN_B)
  }
  __syncthreads();

  // ---------- phase 5: distributed owners, step-gated ----------
  double ll = 0.0;
  float eps4own = 0.f;  // valid in grp 0
  if (grp < 4) {
    const int n1 = 1 + (s >> 6), n2 = 5 + (s >> 4), n3 = 21 + (s >> 2);
    const int a0 = s >> 6, a1 = (s >> 4) & 3, a2 = (s >> 2) & 3, a3 = s & 3;
    float w[4], uv[4];
    float* rb = r_buf + grp * 32;

    // ---- step 0 (all grps 0-3) ----
    float tbv = tbrT[lane];
    float bcv = tbv * __expf(logBL[labs[0] * 33 + lane]);
    bcv /= rsum32(bcv);
    rb[lane] = bcv / tbv;
    if (grp == 0 && s == 0) {
      ll += (double)(bcv * logBL[labs[0] * 33 + lane]);
      WU128M(w, uv, rb)
      const float lb0 = logBL[labs[1] * 33 + lane], lb1 = logBL[labs[2] * 33 + lane];
      const float lb2 = logBL[labs[3] * 33 + lane], lb3 = logBL[labs[4] * 33 + lane];
      float b0 = tbrT[1 * 32 + lane] * __expf(lb0);
      float b1 = tbrT[2 * 32 + lane] * __expf(lb1);
      float b2 = tbrT[3 * 32 + lane] * __expf(lb2);
      float b3 = tbrT[4 * 32 + lane] * __expf(lb3);
      float s0 = b0, s1 = b1, s2 = b2, s3 = b3;
      rsum32x4(s0, s1, s2, s3);
      b0 /= s0; b1 /= s1; b2 /= s2; b3 /= s3;
      ll += (double)(b0 * uv[0]) + (double)(b0 * w[0] * lb0);
      ll += (double)(b1 * uv[1]) + (double)(b1 * w[1] * lb1);
      ll += (double)(b2 * uv[2]) + (double)(b2 * w[2] * lb2);
      ll += (double)(b3 * uv[3]) + (double)(b3 * w[3] * lb3);
    } else {
      WONLY128M(w, rb)
    }

    // ---- step 1 (all grps 0-3) ----
    tbv = tbrT[n1 * 32 + lane];
    bcv = tbv * __expf(logBL[labs[n1] * 33 + lane]);
    bcv /= rsum32(bcv);
    rb[lane] = (bcv * w[a0]) / tbv;
    if (grp == 1 && (s & 63) == 0) {
      WU128M(w, uv, rb)
      const int cb = 5 + 4 * (s >> 6);
      const float lb0 = logBL[labs[cb + 0] * 33 + lane], lb1 = logBL[labs[cb + 1] * 33 + lane];
      const float lb2 = logBL[labs[cb + 2] * 33 + lane], lb3 = logBL[labs[cb + 3] * 33 + lane];
      float b0 = tbrT[(cb + 0) * 32 + lane] * __expf(lb0);
      float b1 = tbrT[(cb + 1) * 32 + lane] * __expf(lb1);
      float b2 = tbrT[(cb + 2) * 32 + lane] * __expf(lb2);
      float b3 = tbrT[(cb + 3) * 32 + lane] * __expf(lb3);
      float s0 = b0, s1 = b1, s2 = b2, s3 = b3;
      rsum32x4(s0, s1, s2, s3);
      b0 /= s0; b1 /= s1; b2 /= s2; b3 /= s3;
      ll += (double)(b0 * uv[0]) + (double)(b0 * w[0] * lb0);
      ll += (double)(b1 * uv[1]) + (double)(b1 * w[1] * lb1);
      ll += (double)(b2 * uv[2]) + (double)(b2 * w[2] * lb2);
      ll += (double)(b3 * uv[3]) + (double)(b3 * w[3] * lb3);
    } else {
      WONLY128M(w, rb)
    }

    // ---- step 2 (grps 0,2,3) ----
    if (grp != 1) {
      tbv = tbrT[n2 * 32 + lane];
      bcv = tbv * __expf(logBL[labs[n2] * 33 + lane]);
      bcv /= rsum32(bcv);
      rb[lane] = (bcv * w[a1]) / tbv;
      if (grp == 2 && (s & 15) == 0) {
        WU128M(w, uv, rb)
        const int cb = 21 + 4 * (s >> 4);
        const float lb0 = logBL[labs[cb + 0] * 33 + lane], lb1 = logBL[labs[cb + 1] * 33 + lane];
        const float lb2 = logBL[labs[cb + 2] * 33 + lane], lb3 = logBL[labs[cb + 3] * 33 + lane];
        float b0 = tbrT[(cb + 0) * 32 + lane] * __expf(lb0);
        float b1 = tbrT[(cb + 1) * 32 + lane] * __expf(lb1);
        float b2 = tbrT[(cb + 2) * 32 + lane] * __expf(lb2);
        float b3 = tbrT[(cb + 3) * 32 + lane] * __expf(lb3);
        float s0 = b0, s1 = b1, s2 = b2, s3 = b3;
        rsum32x4(s0, s1, s2, s3);
        b0 /= s0; b1 /= s1; b2 /= s2; b3 /= s3;
        ll += (double)(b0 * uv[0]) + (double)(b0 * w[0] * lb0);
        ll += (double)(b1 * uv[1]) + (double)(b1 * w[1] * lb1);
        ll += (double)(b2 * uv[2]) + (double)(b2 * w[2] * lb2);
        ll += (double)(b3 * uv[3]) + (double)(b3 * w[3] * lb3);
      } else {
        WONLY128M(w, rb)
      }
    }

    // ---- step 3 (grps 0,3) ----
    if (grp == 0 || grp == 3) {
      tbv = tbrT[n3 * 32 + lane];
      bcv = tbv * __expf(logBL[labs[n3] * 33 + lane]);
      bcv /= rsum32(bcv);
      rb[lane] = (bcv * w[a2]) / tbv;
      if (grp == 3 && (s & 3) == 0) {
        WU128M(w, uv, rb)
        const int cb = s & ~3;
#pragma unroll
        for (int l = 0; l < 4; ++l) {
          const int ci = cb + l;
          const float bc = ws[OFF_B4 + ci * 32 + lane];
          const float e = bc * w[l];
          ll += (double)(bc * uv[l]) + (double)(e * logBL[labs[85 + ci] * 33 + lane]);
        }
      } else {
        WONLY128M(w, rb)
      }
      eps4own = ownb[lane] * w[a3];
    }
  }
  __syncthreads();

  // ---------- phase 6: subtree down sweep ----------
  if (grp == 0) {
    r_buf[lane] = eps4own / tbS[lane];
    float w[4], u[4];
    WU128M(w, u, r_buf)
#pragma unroll
    for (int l = 0; l < 4; ++l) {
      const int lab = labs[341 + l];
      const float tbv = tbS[(1 + l) * 32 + lane];
      float bcv = tbv * __expf(logBL[lab * 33 + lane]);
      bcv /= rsum32(bcv);
      const float e = bcv * w[l];
      ll += (double)(bcv * u[l]) + (double)(e * logBL[lab * 33 + lane]);
      tbS[(1 + l) * 32 + lane] = e / tbv;
    }
  }
  __syncthreads();
  if (grp < 4) {
    const int p = grp;
    r_buf[p * 32 + lane] = tbS[(1 + p) * 32 + lane];
    float w[4], u[4];
    WU128M(w, u, r_buf + p * 32)
#pragma unroll
    for (int l = 0; l < 4; ++l) {
      const int q = p * 4 + l;
      const int lab = labs[345 + q];
      const float tbv = tbS[(5 + q) * 32 + lane];
      float bcv = tbv * __expf(logBL[lab * 33 + lane]);
      bcv /= rsum32(bcv);
      const float e = bcv * w[l];
      ll += (double)(bcv * u[l]) + (double)(e * logBL[lab * 33 + lane]);
      tbS[(5 + q) * 32 + lane] = e / tbv;
    }
  }
  __syncthreads();
  {  // d2: 16 L6 parents, one per group
    const int p = grp;
    float* rb0 = r_buf + grp * 32;
    rb0[lane] = tbS[(5 + p) * 32 + lane];
    float w[4], u[4];
    WU128M(w, u, rb0)
#pragma unroll
    for (int l = 0; l < 4; ++l) {
      const int q = p * 4 + l;
      const float lb = logBL[labs[361 + q] * 33 + lane];
      const float lp = sPt[l * 33 + lane];
      float b = __expf(lp + lb);
      b /= rsum32(b);
      const float e = b * w[l];
      ll += (double)(b * u[l]) + (double)(e * lb) + (double)(e * lp);
    }
  }

  // ---------- phase 7: partials + tree finalize ----------
#pragma unroll
  for (int k = 32; k >= 1; k >>= 1) ll += __shfl_xor(ll, k);
  double* rbd = (double*)r_buf;
  __syncthreads();
  if ((t & 63) == 0) rbd[t >> 6] = ll;
  __syncthreads();
  if (t == 0) {
    partd[s] = ((rbd[0] + rbd[1]) + (rbd[2] + rbd[3])) +
               ((rbd[4] + rbd[5]) + (rbd[6] + rbd[7]));
    __threadfence();
    int f = 0;
    if (atomicAdd(&wsi[IC2 + 32 * (s >> 4)], 1) == 15)
      if (atomicAdd(&wsi[IROOT2], 1) == 15) f = 1;
    fin = f;
  }
  __syncthreads();
  if (fin) {
    __threadfence();
    if (t < 64) {
      double v = 0.0;
      for (int k = t; k < 256; k += 64) v += partd[k];
#pragma unroll
      for (int k = 32; k >= 1; k >>= 1) v += __shfl_xor(v, k);
      if (t == 0) out[0] = (float)v;
    }
  }
}

extern "C" void kernel_launch(void* const* d_in, const int* in_sizes, int n_in,
                              void* d_out, int out_size, void* d_ws, size_t ws_size,
                              hipStream_t stream) {
  (void)in_sizes; (void)n_in; (void)out_size;
  const int* labels = (const int*)d_in[0];
  const float* A = (const float*)d_in[1];
  const float* B = (const float*)d_in[2];
  const float* Pi = (const float*)d_in[3];
  const float* SP = (const float*)d_in[4];
  float* ws = (float*)d_ws;
  float* out = (float*)d_out;

  // ws_size is constant across calls -> host branch is graph-capture-safe.
  if (ws_size >= WS_NEED_BYTES) {
    hipLaunchKernelGGL(k_up_p, dim3(256), dim3(512), 0, stream,
                       labels, A, B, Pi, SP, ws);
    hipLaunchKernelGGL(k_down_p, dim3(256), dim3(512), 0, stream,
                       labels, ws, ws, out);
  } else {
    hipLaunchKernelGGL(k_up_f, dim3(256), dim3(256), 0, stream,
                       labels, A, B, Pi, SP, ws);
    hipLaunchKernelGGL(k_down_f, dim3(256), dim3(512), 0, stream,
                       labels, A, B, Pi, SP, ws, out);
  }
}

// Round 12
// 96.548 us; speedup vs baseline: 1.5389x; 1.5389x over previous
//
#include <hip/hip_runtime.h>

// HTMM: C=32 states, L=4 fanout, M=128 symbols, DEPTH=7.
// Level starts: {0,1,5,21,85,341,1365,5461,21845}.
// R24 = R22 VERBATIM (revert of R23).
// R23 post-mortem: aspL/logBL (extra LDS tables + dual-orientation W loads
// from LDS) flipped the register allocator into spilling the W set to
// scratch: FETCH 0.7MB->60MB, WRITE 16KB->95MB per dispatch, k_down_p
// 39->80us. In R16-R22 the X-macro W "registers" were serviced by cheap
// per-use ds_reads (VGPR ~120, no global traffic); R23 extended W's live
// range and the allocator materialized+spilled. Lesson: this kernel sits
// on a codegen knife-edge; FETCH/WRITE are the tripwire counters.
// R22 = persist path (tables+tbS persisted by k_up_p; k_down_p stages from
// L2, P3 de-serialized via disjoint rows, P5 step-gated, float4 staging,
// ALG/logB register-prefetched at kernel start). Measured 95.1us bench.
// Floor arithmetic: harness fill 39.4 + fixed ~15 + kernels ~40.

static constexpr int OFF_B4   = 0;      // level-4 betas [s*32+i] (8192 f)
static constexpr int OFF_PART = 8192;   // 256 doubles (512 f)
static constexpr int IC2      = 9760;   // 16 finalize counters, stride 32 ints
static constexpr int IROOT2   = 10272;  // finalize root counter
static constexpr int OFF_ASP  = 10304;  // asp, stride-132 layout (4224 f)
static constexpr int OFF_RB   = 14528;  // smB^T linear (4224 f)
static constexpr int OFF_LRB  = 18752;  // log smB^T (4224 f)
static constexpr int OFF_LSP  = 22976;  // log sPt (132 f, +pad)
static constexpr int OFF_ALG  = 23120;  // ALG rows [J*128+lane*4] (4096 f)
static constexpr int OFF_TBO  = 27216;  // per-block tbS, stride 672 (172032 f)
static constexpr size_t WS_NEED_BYTES = (size_t)(OFF_TBO + 256 * 672) * 4;

__device__ __forceinline__ float rsum32(float v) {
#pragma unroll
  for (int k = 1; k <= 16; k <<= 1) v += __shfl_xor(v, k);
  return v;
}
__device__ __forceinline__ void rsum32x2(float& a, float& b) {
#pragma unroll
  for (int k = 1; k <= 16; k <<= 1) { a += __shfl_xor(a, k); b += __shfl_xor(b, k); }
}
__device__ __forceinline__ void rsum32x4(float& a, float& b, float& c, float& d) {
#pragma unroll
  for (int k = 1; k <= 16; k <<= 1) {
    a += __shfl_xor(a, k); b += __shfl_xor(b, k);
    c += __shfl_xor(c, k); d += __shfl_xor(d, k);
  }
}
__device__ __forceinline__ float4 exp4f(float4 v) {
  return make_float4(__expf(v.x), __expf(v.y), __expf(v.z), __expf(v.w));
}

// ---------------- register-file W matrix: 32 named float4 ----------------
#define W_DECL float4 Wr0, Wr1, Wr2, Wr3, Wr4, Wr5, Wr6, Wr7, Wr8, Wr9,     \
    Wr10, Wr11, Wr12, Wr13, Wr14, Wr15, Wr16, Wr17, Wr18, Wr19, Wr20, Wr21, \
    Wr22, Wr23, Wr24, Wr25, Wr26, Wr27, Wr28, Wr29, Wr30, Wr31;

#define REPW(X) X(0,Wr0) X(1,Wr1) X(2,Wr2) X(3,Wr3) X(4,Wr4) X(5,Wr5)       \
    X(6,Wr6) X(7,Wr7) X(8,Wr8) X(9,Wr9) X(10,Wr10) X(11,Wr11) X(12,Wr12)    \
    X(13,Wr13) X(14,Wr14) X(15,Wr15) X(16,Wr16) X(17,Wr17) X(18,Wr18)       \
    X(19,Wr19) X(20,Wr20) X(21,Wr21) X(22,Wr22) X(23,Wr23) X(24,Wr24)       \
    X(25,Wr25) X(26,Wr26) X(27,Wr27) X(28,Wr28) X(29,Wr29) X(30,Wr30)       \
    X(31,Wr31)

#define REPQ(X) X(0,Wr0,Wr1,Wr2,Wr3) X(1,Wr4,Wr5,Wr6,Wr7)                   \
    X(2,Wr8,Wr9,Wr10,Wr11) X(3,Wr12,Wr13,Wr14,Wr15) X(4,Wr16,Wr17,Wr18,Wr19)\
    X(5,Wr20,Wr21,Wr22,Wr23) X(6,Wr24,Wr25,Wr26,Wr27) X(7,Wr28,Wr29,Wr30,Wr31)

// load up-orientation row (lane) from scr (stride 132)
#define WLD_B(J, WJ) WJ = *(const float4*)(scrW_ + 4 * (J));
#define W_LOADUP { const float* scrW_ = scr + lane * 132; REPW(WLD_B) }

// load down-orientation from persisted asp table in ws (row J, cols 4lane..)
#define WLDDN_B(J, WJ) WJ = *(const float4*)(wsASP_ + (J) * 132 + lane * 4);

// tb = dot(W_row_lane, X[0..127])
#define DOT_B(J, WJ) { const float4 x_ = *(const float4*)(dXp_ + 4 * (J));   \
    dt0_ = fmaf(WJ.x, x_.x, dt0_); dt1_ = fmaf(WJ.y, x_.y, dt1_);            \
    dt2_ = fmaf(WJ.z, x_.z, dt2_); dt3_ = fmaf(WJ.w, x_.w, dt3_); }
#define DOT128M(OUT, XP) { const float* dXp_ = (XP);                         \
    float dt0_ = 0.f, dt1_ = 0.f, dt2_ = 0.f, dt3_ = 0.f;                    \
    REPW(DOT_B) (OUT) = (dt0_ + dt1_) + (dt2_ + dt3_); }

// two parents, shared W row
#define DOTX2_B(J, WJ) {                                                     \
    const float4 x_ = *(const float4*)(dXp0_ + 4 * (J));                     \
    const float4 y_ = *(const float4*)(dXp1_ + 4 * (J));                     \
    da0_ = fmaf(WJ.x, x_.x, da0_); db0_ = fmaf(WJ.x, y_.x, db0_);            \
    da1_ = fmaf(WJ.y, x_.y, da1_); db1_ = fmaf(WJ.y, y_.y, db1_);            \
    da2_ = fmaf(WJ.z, x_.z, da2_); db2_ = fmaf(WJ.z, y_.z, db2_);            \
    da3_ = fmaf(WJ.w, x_.w, da3_); db3_ = fmaf(WJ.w, y_.w, db3_); }
#define DOT128X2M(O0, O1, XP0, XP1) {                                        \
    const float* dXp0_ = (XP0); const float* dXp1_ = (XP1);                  \
    float da0_ = 0.f, da1_ = 0.f, da2_ = 0.f, da3_ = 0.f;                    \
    float db0_ = 0.f, db1_ = 0.f, db2_ = 0.f, db3_ = 0.f;                    \
    REPW(DOTX2_B) (O0) = (da0_ + da1_) + (da2_ + da3_);                      \
    (O1) = (db0_ + db1_) + (db2_ + db3_); }

// path walk: w only.  w_l += W[i].l * rb[i]
#define WO_B(Q, WA, WB, WC, WD) {                                            \
    const float4 rv_ = *(const float4*)(rbp_ + 4 * (Q));                     \
    ww0_ = fmaf(WA.x, rv_.x, ww0_); ww1_ = fmaf(WA.y, rv_.x, ww1_);          \
    ww2_ = fmaf(WA.z, rv_.x, ww2_); ww3_ = fmaf(WA.w, rv_.x, ww3_);          \
    ww0_ = fmaf(WB.x, rv_.y, ww0_); ww1_ = fmaf(WB.y, rv_.y, ww1_);          \
    ww2_ = fmaf(WB.z, rv_.y, ww2_); ww3_ = fmaf(WB.w, rv_.y, ww3_);          \
    ww0_ = fmaf(WC.x, rv_.z, ww0_); ww1_ = fmaf(WC.y, rv_.z, ww1_);          \
    ww2_ = fmaf(WC.z, rv_.z, ww2_); ww3_ = fmaf(WC.w, rv_.z, ww3_);          \
    ww0_ = fmaf(WD.x, rv_.w, ww0_); ww1_ = fmaf(WD.y, rv_.w, ww1_);          \
    ww2_ = fmaf(WD.z, rv_.w, ww2_); ww3_ = fmaf(WD.w, rv_.w, ww3_); }
#define WONLY128M(W, RBP) { const float* rbp_ = (RBP);                       \
    float ww0_ = 0.f, ww1_ = 0.f, ww2_ = 0.f, ww3_ = 0.f;                    \
    REPQ(WO_B) (W)[0] = ww0_; (W)[1] = ww1_; (W)[2] = ww2_; (W)[3] = ww3_; }

// w + u (u from ALG rows in scr)
#define WU_SUB(ROW, WX, RC) {                                                \
    const float4 av_ = *(const float4*)(ALGp_ + (ROW) * 128);                \
    ww0_ = fmaf(WX.x, RC, ww0_); uu0_ = fmaf(av_.x, RC, uu0_);               \
    ww1_ = fmaf(WX.y, RC, ww1_); uu1_ = fmaf(av_.y, RC, uu1_);               \
    ww2_ = fmaf(WX.z, RC, ww2_); uu2_ = fmaf(av_.z, RC, uu2_);               \
    ww3_ = fmaf(WX.w, RC, ww3_); uu3_ = fmaf(av_.w, RC, uu3_); }
#define WU_B(Q, WA, WB, WC, WD) {                                            \
    const float4 rv_ = *(const float4*)(rbp_ + 4 * (Q));                     \
    WU_SUB(4 * (Q) + 0, WA, rv_.x) WU_SUB(4 * (Q) + 1, WB, rv_.y)            \
    WU_SUB(4 * (Q) + 2, WC, rv_.z) WU_SUB(4 * (Q) + 3, WD, rv_.w) }
#define WU128M(W, U, RBP) { const float* rbp_ = (RBP);                       \
    const float* ALGp_ = scr + lane * 4;                                     \
    float ww0_ = 0.f, ww1_ = 0.f, ww2_ = 0.f, ww3_ = 0.f;                    \
    float uu0_ = 0.f, uu1_ = 0.f, uu2_ = 0.f, uu3_ = 0.f;                    \
    REPQ(WU_B) (W)[0] = ww0_; (W)[1] = ww1_; (W)[2] = ww2_; (W)[3] = ww3_;   \
    (U)[0] = uu0_; (U)[1] = uu1_; (U)[2] = uu2_; (U)[3] = uu3_; }

// two parents share the ALG read stream
#define WUX2_SUB(ROW, WX, RC0, RC1) {                                        \
    const float4 av_ = *(const float4*)(ALGp_ + (ROW) * 128);                \
    wa0_ = fmaf(WX.x, RC0, wa0_); wb0_ = fmaf(WX.x, RC1, wb0_);              \
    ua0_ = fmaf(av_.x, RC0, ua0_); ub0_ = fmaf(av_.x, RC1, ub0_);            \
    wa1_ = fmaf(WX.y, RC0, wa1_); wb1_ = fmaf(WX.y, RC1, wb1_);              \
    ua1_ = fmaf(av_.y, RC0, ua1_); ub1_ = fmaf(av_.y, RC1, ub1_);            \
    wa2_ = fmaf(WX.z, RC0, wa2_); wb2_ = fmaf(WX.z, RC1, wb2_);              \
    ua2_ = fmaf(av_.z, RC0, ua2_); ub2_ = fmaf(av_.z, RC1, ub2_);            \
    wa3_ = fmaf(WX.w, RC0, wa3_); wb3_ = fmaf(WX.w, RC1, wb3_);              \
    ua3_ = fmaf(av_.w, RC0, ua3_); ub3_ = fmaf(av_.w, RC1, ub3_); }
#define WUX2_B(Q, WA, WB, WC, WD) {                                          \
    const float4 rv0_ = *(const float4*)(rbp0_ + 4 * (Q));                   \
    const float4 rv1_ = *(const float4*)(rbp1_ + 4 * (Q));                   \
    WUX2_SUB(4 * (Q) + 0, WA, rv0_.x, rv1_.x)                                \
    WUX2_SUB(4 * (Q) + 1, WB, rv0_.y, rv1_.y)                                \
    WUX2_SUB(4 * (Q) + 2, WC, rv0_.z, rv1_.z)                                \
    WUX2_SUB(4 * (Q) + 3, WD, rv0_.w, rv1_.w) }
#define WU128X2M(W0, U0, W1, U1, RBP0, RBP1) {                               \
    const float* rbp0_ = (RBP0); const float* rbp1_ = (RBP1);                \
    const float* ALGp_ = scr + lane * 4;                                     \
    float wa0_ = 0.f, wa1_ = 0.f, wa2_ = 0.f, wa3_ = 0.f;                    \
    float ua0_ = 0.f, ua1_ = 0.f, ua2_ = 0.f, ua3_ = 0.f;                    \
    float wb0_ = 0.f, wb1_ = 0.f, wb2_ = 0.f, wb3_ = 0.f;                    \
    float ub0_ = 0.f, ub1_ = 0.f, ub2_ = 0.f, ub3_ = 0.f;                    \
    REPQ(WUX2_B)                                                             \
    (W0)[0] = wa0_; (W0)[1] = wa1_; (W0)[2] = wa2_; (W0)[3] = wa3_;          \
    (U0)[0] = ua0_; (U0)[1] = ua1_; (U0)[2] = ua2_; (U0)[3] = ua3_;          \
    (W1)[0] = wb0_; (W1)[1] = wb1_; (W1)[2] = wb2_; (W1)[3] = wb3_;          \
    (U1)[0] = ub0_; (U1)[1] = ub1_; (U1)[2] = ub2_; (U1)[3] = ub3_; }

// phase-4 rebuild (FALLBACK k_down only): W -> down orient; ALG into scr
#define WRD_B(J, WJ) { const float4 av = A4[(J) * 32 + lane];                \
    const float4 e = exp4f(av);                                              \
    const float4 asp = make_float4(e.x * inv4.x, e.y * inv4.y,               \
                                   e.z * inv4.z, e.w * inv4.w);              \
    WJ = asp;                                                                \
    if (grp == ((J) >> 1))                                                   \
      *(float4*)(scr + (J) * 128 + lane * 4) =                               \
          make_float4(asp.x * (av.x - sub4.x), asp.y * (av.y - sub4.y),      \
                      asp.z * (av.z - sub4.z), asp.w * (av.w - sub4.w)); }

// ======================================================================
// ===================== FALLBACK PATH (R18, proven) ====================
// ======================================================================
__global__ __launch_bounds__(256, 1) void k_up_f(const int* __restrict__ labels,
                                                 const float* __restrict__ A,
                                                 const float* __restrict__ B,
                                                 const float* __restrict__ Pi,
                                                 const float* __restrict__ SP,
                                                 float* __restrict__ ws) {
  __shared__ __align__(16) float scr[4224];
  __shared__ __align__(16) float regB[4224];
  __shared__ __align__(16) float sPt[132];
  __shared__ int labs[425];
  const int t = threadIdx.x, lane = t & 31, grp = t >> 5;
  const int s = blockIdx.x;
  int* wsi = (int*)ws;
  const float4* A4 = (const float4*)A;
  const float4* B4 = (const float4*)B;

  if (t < 16) wsi[IC2 + 32 * t] = 0;
  else if (t == 16) wsi[IROOT2] = 0;

  const float sv0 = SP[0], sv1 = SP[1], sv2 = SP[2], sv3 = SP[3];
  const float sp0 = __expf(sv0), sp1 = __expf(sv1), sp2 = __expf(sv2), sp3 = __expf(sv3);
  const float spsum = sp0 + sp1 + sp2 + sp3;
  const float spinv = 1.f / spsum;
  float4 c4 = make_float4(0.f, 0.f, 0.f, 0.f);
  for (int i = 0; i < 32; ++i) {
    const float4 e = exp4f(A4[i * 32 + lane]);
    c4.x += e.x; c4.y += e.y; c4.z += e.z; c4.w += e.w;
  }
  const float4 inv4 = make_float4(sp0 * spinv / c4.x, sp1 * spinv / c4.y,
                                  sp2 * spinv / c4.z, sp3 * spinv / c4.w);
#pragma unroll
  for (int k = 0; k < 4; ++k) {
    const int i = grp * 4 + k;
    const float4 e = exp4f(A4[i * 32 + lane]);
    *(float4*)(scr + i * 132 + 4 * lane) =
        make_float4(e.x * inv4.x, e.y * inv4.y, e.z * inv4.z, e.w * inv4.w);
  }
#pragma unroll
  for (int rI = 0; rI < 4; ++rI) {
    const int i = grp + rI * 8;
    const float4 e = exp4f(B4[i * 32 + lane]);
    const float sinv = 1.f / rsum32(e.x + e.y + e.z + e.w);
    regB[(4 * lane + 0) * 33 + i] = e.x * sinv;
    regB[(4 * lane + 1) * 33 + i] = e.y * sinv;
    regB[(4 * lane + 2) * 33 + i] = e.z * sinv;
    regB[(4 * lane + 3) * 33 + i] = e.w * sinv;
  }
  if (grp < 4) {
    const float e = __expf(Pi[lane * 4 + grp]);
    sPt[grp * 33 + lane] = e / rsum32(e);
  }
  if (t < 84) {
    int g, d;
    if (t < 4) { g = 341 + 4 * s + t; d = 341 + t; }
    else if (t < 20) { g = 1365 + 16 * s + (t - 4); d = 345 + (t - 4); }
    else { g = 5461 + 64 * s + (t - 20); d = 361 + (t - 20); }
    labs[d] = labels[g];
  }
  if (t == 84) labs[85 + (s & 255)] = labels[85 + s];
  __syncthreads();
  W_DECL
  W_LOADUP
  __syncthreads();

#pragma unroll
  for (int h = 0; h < 2; ++h) {
    const int q0 = grp + 32 * h, q1 = q0 + 8, q2 = q0 + 16, q3 = q0 + 24;
    float v0 = sPt[(q0 & 3) * 33 + lane] * regB[labs[361 + q0] * 33 + lane];
    float v1 = sPt[(q1 & 3) * 33 + lane] * regB[labs[361 + q1] * 33 + lane];
    float v2 = sPt[(q2 & 3) * 33 + lane] * regB[labs[361 + q2] * 33 + lane];
    float v3 = sPt[(q3 & 3) * 33 + lane] * regB[labs[361 + q3] * 33 + lane];
    float s0 = v0, s1 = v1, s2 = v2, s3 = v3;
    rsum32x4(s0, s1, s2, s3);
    scr[(q0 >> 2) * 128 + lane * 4 + (q0 & 3)] = v0 / s0;
    scr[(q1 >> 2) * 128 + lane * 4 + (q1 & 3)] = v1 / s1;
    scr[(q2 >> 2) * 128 + lane * 4 + (q2 & 3)] = v2 / s2;
    scr[(q3 >> 2) * 128 + lane * 4 + (q3 & 3)] = v3 / s3;
  }
  __syncthreads();
  {
    const int p0 = grp, p1 = grp + 8;
    float tb0, tb1;
    DOT128X2M(tb0, tb1, scr + p0 * 128, scr + p1 * 128)
    float bl0 = tb0 * regB[labs[345 + p0] * 33 + lane];
    float bl1 = tb1 * regB[labs[345 + p1] * 33 + lane];
    float s0 = bl0, s1 = bl1;
    rsum32x2(s0, s1);
    bl0 /= s0; bl1 /= s1;
    scr[2048 + (p0 >> 2) * 128 + lane * 4 + (p0 & 3)] = bl0;
    scr[2048 + (p1 >> 2) * 128 + lane * 4 + (p1 & 3)] = bl1;
  }
  __syncthreads();
  if (grp < 4) {
    float tb;
    DOT128M(tb, scr + 2048 + grp * 128)
    float bl = tb * regB[labs[341 + grp] * 33 + lane];
    bl /= rsum32(bl);
    scr[2560 + lane * 4 + grp] = bl;
  }
  __syncthreads();
  if (grp == 0) {
    float tb;
    DOT128M(tb, scr + 2560)
    float bl = tb * regB[labs[85 + (s & 255)] * 33 + lane];
    bl /= rsum32(bl);
    ws[OFF_B4 + s * 32 + lane] = bl;
  }
}

__global__ __launch_bounds__(512, 1)
void k_down_f(const int* __restrict__ labels,
              const float* __restrict__ A,
              const float* __restrict__ B,
              const float* __restrict__ Pi,
              const float* __restrict__ SP,
              float* __restrict__ ws,
              float* __restrict__ out) {
  __shared__ __align__(16) float scr[6144];
  __shared__ __align__(16) float regB[4224];
  __shared__ __align__(16) float sPt[132];
  __shared__ __align__(16) float tbrT[2720];
  __shared__ __align__(16) float tbS[672];
  __shared__ __align__(16) float ownb[32];
  __shared__ __align__(16) float r_buf[512];
  __shared__ int labs[425];
  __shared__ int fin;
  const int t = threadIdx.x, lane = t & 31, grp = t >> 5;
  const int s = blockIdx.x;
  int* wsi = (int*)ws;
  double* partd = (double*)(ws + OFF_PART);
  const float4* A4 = (const float4*)A;
  const float4* B4 = (const float4*)B;

  float pf0[8], pf1[8];
#pragma unroll
  for (int h = 0; h < 2; ++h) {
    const int p0 = grp + 32 * h, p1 = p0 + 16;
#pragma unroll
    for (int l = 0; l < 4; ++l) {
      pf0[h * 4 + l] = ws[OFF_B4 + (p0 * 4 + l) * 32 + lane];
      pf1[h * 4 + l] = ws[OFF_B4 + (p1 * 4 + l) * 32 + lane];
    }
  }

  const float sv0 = SP[0], sv1 = SP[1], sv2 = SP[2], sv3 = SP[3];
  const float sp0 = __expf(sv0), sp1 = __expf(sv1), sp2 = __expf(sv2), sp3 = __expf(sv3);
  const float spsum = sp0 + sp1 + sp2 + sp3;
  const float spinv = 1.f / spsum;
  const float lss = __logf(spsum);
  float4 c4 = make_float4(0.f, 0.f, 0.f, 0.f);
  for (int i = 0; i < 32; ++i) {
    const float4 e = exp4f(A4[i * 32 + lane]);
    c4.x += e.x; c4.y += e.y; c4.z += e.z; c4.w += e.w;
  }
  const float4 inv4 = make_float4(sp0 * spinv / c4.x, sp1 * spinv / c4.y,
                                  sp2 * spinv / c4.z, sp3 * spinv / c4.w);
  const float4 sub4 = make_float4(__logf(c4.x) - (sv0 - lss), __logf(c4.y) - (sv1 - lss),
                                  __logf(c4.z) - (sv2 - lss), __logf(c4.w) - (sv3 - lss));
#pragma unroll
  for (int k = 0; k < 2; ++k) {
    const int i = grp * 2 + k;
    const float4 e = exp4f(A4[i * 32 + lane]);
    *(float4*)(scr + i * 132 + 4 * lane) =
        make_float4(e.x * inv4.x, e.y * inv4.y, e.z * inv4.z, e.w * inv4.w);
  }
#pragma unroll
  for (int rI = 0; rI < 2; ++rI) {
    const int i = grp + rI * 16;
    const float4 e = exp4f(B4[i * 32 + lane]);
    const float sinv = 1.f / rsum32(e.x + e.y + e.z + e.w);
    regB[(4 * lane + 0) * 33 + i] = e.x * sinv;
    regB[(4 * lane + 1) * 33 + i] = e.y * sinv;
    regB[(4 * lane + 2) * 33 + i] = e.z * sinv;
    regB[(4 * lane + 3) * 33 + i] = e.w * sinv;
  }
  if (grp < 4) {
    const float e = __expf(Pi[lane * 4 + grp]);
    sPt[grp * 33 + lane] = e / rsum32(e);
  }
  for (int idx = t; idx < 341; idx += 512) labs[idx] = labels[idx];
  if (t < 84) {
    int g, d;
    if (t < 4) { g = 341 + 4 * s + t; d = 341 + t; }
    else if (t < 20) { g = 1365 + 16 * s + (t - 4); d = 345 + (t - 4); }
    else { g = 5461 + 64 * s + (t - 20); d = 361 + (t - 20); }
    labs[d] = labels[g];
  }
  __syncthreads();
  W_DECL
  W_LOADUP
  __syncthreads();

  {
    const int q0 = grp, q1 = grp + 16, q2 = grp + 32, q3 = grp + 48;
    float v0 = sPt[(q0 & 3) * 33 + lane] * regB[labs[361 + q0] * 33 + lane];
    float v1 = sPt[(q1 & 3) * 33 + lane] * regB[labs[361 + q1] * 33 + lane];
    float v2 = sPt[(q2 & 3) * 33 + lane] * regB[labs[361 + q2] * 33 + lane];
    float v3 = sPt[(q3 & 3) * 33 + lane] * regB[labs[361 + q3] * 33 + lane];
    float s0 = v0, s1 = v1, s2 = v2, s3 = v3;
    rsum32x4(s0, s1, s2, s3);
    scr[(q0 >> 2) * 128 + lane * 4 + (q0 & 3)] = v0 / s0;
    scr[(q1 >> 2) * 128 + lane * 4 + (q1 & 3)] = v1 / s1;
    scr[(q2 >> 2) * 128 + lane * 4 + (q2 & 3)] = v2 / s2;
    scr[(q3 >> 2) * 128 + lane * 4 + (q3 & 3)] = v3 / s3;
  }
  __syncthreads();
  if (grp < 8) {
    const int p0 = grp, p1 = grp + 8;
    float tb0, tb1;
    DOT128X2M(tb0, tb1, scr + p0 * 128, scr + p1 * 128)
    float bl0 = tb0 * regB[labs[345 + p0] * 33 + lane];
    float bl1 = tb1 * regB[labs[345 + p1] * 33 + lane];
    float s0 = bl0, s1 = bl1;
    rsum32x2(s0, s1);
    bl0 /= s0; bl1 /= s1;
    tbS[(5 + p0) * 32 + lane] = tb0;
    tbS[(5 + p1) * 32 + lane] = tb1;
    scr[2048 + (p0 >> 2) * 128 + lane * 4 + (p0 & 3)] = bl0;
    scr[2048 + (p1 >> 2) * 128 + lane * 4 + (p1 & 3)] = bl1;
  }
  __syncthreads();
  if (grp < 4) {
    float tb;
    DOT128M(tb, scr + 2048 + grp * 128)
    float bl = tb * regB[labs[341 + grp] * 33 + lane];
    bl /= rsum32(bl);
    tbS[(1 + grp) * 32 + lane] = tb;
    scr[2560 + lane * 4 + grp] = bl;
  }
  __syncthreads();
  if (grp == 0) {
    float tb;
    DOT128M(tb, scr + 2560)
    float bl = tb * regB[labs[85 + s] * 33 + lane];
    bl /= rsum32(bl);
    tbS[lane] = tb;
    ownb[lane] = bl;
  }
  __syncthreads();

#pragma unroll
  for (int h = 0; h < 2; ++h) {
    const int p0 = grp + 32 * h, p1 = p0 + 16;
    float* st0 = scr + grp * 128;
    float* st1 = scr + 2048 + grp * 128;
#pragma unroll
    for (int l = 0; l < 4; ++l) {
      st0[lane * 4 + l] = pf0[h * 4 + l];
      st1[lane * 4 + l] = pf1[h * 4 + l];
    }
    float tb0, tb1;
    DOT128X2M(tb0, tb1, st0, st1)
    float bl0 = tb0 * regB[labs[21 + p0] * 33 + lane];
    float bl1 = tb1 * regB[labs[21 + p1] * 33 + lane];
    float s0 = bl0, s1 = bl1;
    rsum32x2(s0, s1);
    bl0 /= s0; bl1 /= s1;
    tbrT[(21 + p0) * 32 + lane] = tb0;
    tbrT[(21 + p1) * 32 + lane] = tb1;
    scr[4096 + (p0 >> 2) * 128 + lane * 4 + (p0 & 3)] = bl0;
    scr[4096 + (p1 >> 2) * 128 + lane * 4 + (p1 & 3)] = bl1;
  }
  __syncthreads();
  {
    const int p = grp;
    float tb;
    DOT128M(tb, scr + 4096 + p * 128)
    float bl = tb * regB[labs[5 + p] * 33 + lane];
    bl /= rsum32(bl);
    tbrT[(5 + p) * 32 + lane] = tb;
    scr[(p >> 2) * 128 + lane * 4 + (p & 3)] = bl;
  }
  __syncthreads();
  if (grp < 4) {
    float tb;
    DOT128M(tb, scr + grp * 128)
    float bl = tb * regB[labs[1 + grp] * 33 + lane];
    bl /= rsum32(bl);
    tbrT[(1 + grp) * 32 + lane] = tb;
    scr[512 + lane * 4 + grp] = bl;
  }
  __syncthreads();
  if (grp == 0) { float tb; DOT128M(tb, scr + 512) tbrT[lane] = tb; }
  __syncthreads();

  for (int idx = t; idx < 4224; idx += 512) regB[idx] = __logf(regB[idx]);
  if (t < 132) sPt[t] = __logf(sPt[t]);
  REPW(WRD_B)
  __syncthreads();

  double ll = 0.0;
  float eps4own = 0.f;
  if (grp < 4) {
    const int n1 = 1 + (s >> 6), n2 = 5 + (s >> 4), n3 = 21 + (s >> 2);
    const int a0 = s >> 6, a1 = (s >> 4) & 3, a2 = (s >> 2) & 3, a3 = s & 3;
    float w[4], uv[4];
    float* rb = r_buf + grp * 32;

    float tbv = tbrT[lane];
    float bcv = tbv * __expf(regB[labs[0] * 33 + lane]);
    bcv /= rsum32(bcv);
    rb[lane] = bcv / tbv;
    if (grp == 0 && s == 0) {
      ll += (double)(bcv * regB[labs[0] * 33 + lane]);
      WU128M(w, uv, rb)
      const float lb0 = regB[labs[1] * 33 + lane], lb1 = regB[labs[2] * 33 + lane];
      const float lb2 = regB[labs[3] * 33 + lane], lb3 = regB[labs[4] * 33 + lane];
      float b0 = tbrT[1 * 32 + lane] * __expf(lb0);
      float b1 = tbrT[2 * 32 + lane] * __expf(lb1);
      float b2 = tbrT[3 * 32 + lane] * __expf(lb2);
      float b3 = tbrT[4 * 32 + lane] * __expf(lb3);
      float s0 = b0, s1 = b1, s2 = b2, s3 = b3;
      rsum32x4(s0, s1, s2, s3);
      b0 /= s0; b1 /= s1; b2 /= s2; b3 /= s3;
      ll += (double)(b0 * uv[0]) + (double)(b0 * w[0] * lb0);
      ll += (double)(b1 * uv[1]) + (double)(b1 * w[1] * lb1);
      ll += (double)(b2 * uv[2]) + (double)(b2 * w[2] * lb2);
      ll += (double)(b3 * uv[3]) + (double)(b3 * w[3] * lb3);
    } else {
      WONLY128M(w, rb)
    }

    tbv = tbrT[n1 * 32 + lane];
    bcv = tbv * __expf(regB[labs[n1] * 33 + lane]);
    bcv /= rsum32(bcv);
    rb[lane] = (bcv * w[a0]) / tbv;
    if (grp == 1 && (s & 63) == 0) {
      WU128M(w, uv, rb)
      const int cb = 5 + 4 * (s >> 6);
      const float lb0 = regB[labs[cb + 0] * 33 + lane], lb1 = regB[labs[cb + 1] * 33 + lane];
      const float lb2 = regB[labs[cb + 2] * 33 + lane], lb3 = regB[labs[cb + 3] * 33 + lane];
      float b0 = tbrT[(cb + 0) * 32 + lane] * __expf(lb0);
      float b1 = tbrT[(cb + 1) * 32 + lane] * __expf(lb1);
      float b2 = tbrT[(cb + 2) * 32 + lane] * __expf(lb2);
      float b3 = tbrT[(cb + 3) * 32 + lane] * __expf(lb3);
      float s0 = b0, s1 = b1, s2 = b2, s3 = b3;
      rsum32x4(s0, s1, s2, s3);
      b0 /= s0; b1 /= s1; b2 /= s2; b3 /= s3;
      ll += (double)(b0 * uv[0]) + (double)(b0 * w[0] * lb0);
      ll += (double)(b1 * uv[1]) + (double)(b1 * w[1] * lb1);
      ll += (double)(b2 * uv[2]) + (double)(b2 * w[2] * lb2);
      ll += (double)(b3 * uv[3]) + (double)(b3 * w[3] * lb3);
    } else {
      WONLY128M(w, rb)
    }

    tbv = tbrT[n2 * 32 + lane];
    bcv = tbv * __expf(regB[labs[n2] * 33 + lane]);
    bcv /= rsum32(bcv);
    rb[lane] = (bcv * w[a1]) / tbv;
    if (grp == 2 && (s & 15) == 0) {
      WU128M(w, uv, rb)
      const int cb = 21 + 4 * (s >> 4);
      const float lb0 = regB[labs[cb + 0] * 33 + lane], lb1 = regB[labs[cb + 1] * 33 + lane];
      const float lb2 = regB[labs[cb + 2] * 33 + lane], lb3 = regB[labs[cb + 3] * 33 + lane];
      float b0 = tbrT[(cb + 0) * 32 + lane] * __expf(lb0);
      float b1 = tbrT[(cb + 1) * 32 + lane] * __expf(lb1);
      float b2 = tbrT[(cb + 2) * 32 + lane] * __expf(lb2);
      float b3 = tbrT[(cb + 3) * 32 + lane] * __expf(lb3);
      float s0 = b0, s1 = b1, s2 = b2, s3 = b3;
      rsum32x4(s0, s1, s2, s3);
      b0 /= s0; b1 /= s1; b2 /= s2; b3 /= s3;
      ll += (double)(b0 * uv[0]) + (double)(b0 * w[0] * lb0);
      ll += (double)(b1 * uv[1]) + (double)(b1 * w[1] * lb1);
      ll += (double)(b2 * uv[2]) + (double)(b2 * w[2] * lb2);
      ll += (double)(b3 * uv[3]) + (double)(b3 * w[3] * lb3);
    } else {
      WONLY128M(w, rb)
    }

    tbv = tbrT[n3 * 32 + lane];
    bcv = tbv * __expf(regB[labs[n3] * 33 + lane]);
    bcv /= rsum32(bcv);
    rb[lane] = (bcv * w[a2]) / tbv;
    if (grp == 3 && (s & 3) == 0) {
      WU128M(w, uv, rb)
      const int cb = s & ~3;
#pragma unroll
      for (int l = 0; l < 4; ++l) {
        const int ci = cb + l;
        const float bc = ws[OFF_B4 + ci * 32 + lane];
        const float e = bc * w[l];
        ll += (double)(bc * uv[l]) + (double)(e * regB[labs[85 + ci] * 33 + lane]);
      }
    } else {
      WONLY128M(w, rb)
    }
    eps4own = ownb[lane] * w[a3];
  }
  __syncthreads();

  if (grp == 0) {
    r_buf[lane] = eps4own / tbS[lane];
    float w[4], u[4];
    WU128M(w, u, r_buf)
#pragma unroll
    for (int l = 0; l < 4; ++l) {
      const int lab = labs[341 + l];
      const float tbv = tbS[(1 + l) * 32 + lane];
      float bcv = tbv * __expf(regB[lab * 33 + lane]);
      bcv /= rsum32(bcv);
      const float e = bcv * w[l];
      ll += (double)(bcv * u[l]) + (double)(e * regB[lab * 33 + lane]);
      tbS[(1 + l) * 32 + lane] = e / tbv;
    }
  }
  __syncthreads();
  if (grp < 4) {
    const int p = grp;
    r_buf[p * 32 + lane] = tbS[(1 + p) * 32 + lane];
    float w[4], u[4];
    WU128M(w, u, r_buf + p * 32)
#pragma unroll
    for (int l = 0; l < 4; ++l) {
      const int q = p * 4 + l;
      const int lab = labs[345 + q];
      const float tbv = tbS[(5 + q) * 32 + lane];
      float bcv = tbv * __expf(regB[lab * 33 + lane]);
      bcv /= rsum32(bcv);
      const float e = bcv * w[l];
      ll += (double)(bcv * u[l]) + (double)(e * regB[lab * 33 + lane]);
      tbS[(5 + q) * 32 + lane] = e / tbv;
    }
  }
  __syncthreads();
  if (grp < 8) {
    const int p0 = grp, p1 = grp + 8;
    float* rb0 = r_buf + grp * 32;
    float* rb1 = r_buf + 256 + grp * 32;
    rb0[lane] = tbS[(5 + p0) * 32 + lane];
    rb1[lane] = tbS[(5 + p1) * 32 + lane];
    float w0[4], u0[4], w1[4], u1[4];
    WU128X2M(w0, u0, w1, u1, rb0, rb1)
#pragma unroll
    for (int l = 0; l < 4; ++l) {
      const int q0 = p0 * 4 + l, q1 = p1 * 4 + l;
      const float lb0 = regB[labs[361 + q0] * 33 + lane];
      const float lb1 = regB[labs[361 + q1] * 33 + lane];
      const float lp = sPt[l * 33 + lane];
      float b0 = __expf(lp + lb0);
      float b1 = __expf(lp + lb1);
      float s0 = b0, s1 = b1;
      rsum32x2(s0, s1);
      b0 /= s0; b1 /= s1;
      const float e0 = b0 * w0[l], e1 = b1 * w1[l];
      ll += (double)(b0 * u0[l]) + (double)(e0 * lb0) + (double)(e0 * lp);
      ll += (double)(b1 * u1[l]) + (double)(e1 * lb1) + (double)(e1 * lp);
    }
  }

#pragma unroll
  for (int k = 32; k >= 1; k >>= 1) ll += __shfl_xor(ll, k);
  double* rbd = (double*)r_buf;
  __syncthreads();
  if ((t & 63) == 0) rbd[t >> 6] = ll;
  __syncthreads();
  if (t == 0) {
    partd[s] = ((rbd[0] + rbd[1]) + (rbd[2] + rbd[3])) +
               ((rbd[4] + rbd[5]) + (rbd[6] + rbd[7]));
    __threadfence();
    int f = 0;
    if (atomicAdd(&wsi[IC2 + 32 * (s >> 4)], 1) == 15)
      if (atomicAdd(&wsi[IROOT2], 1) == 15) f = 1;
    fin = f;
  }
  __syncthreads();
  if (fin) {
    __threadfence();
    if (t < 64) {
      double v = 0.0;
      for (int k = t; k < 256; k += 64) v += partd[k];
#pragma unroll
      for (int k = 32; k >= 1; k >>= 1) v += __shfl_xor(v, k);
      if (t == 0) out[0] = (float)v;
    }
  }
}

// ======================================================================
// ================= PERSIST PATH (R21 design + R22 cuts) ===============
// ======================================================================
__global__ __launch_bounds__(512, 1) void k_up_p(const int* __restrict__ labels,
                                                 const float* __restrict__ A,
                                                 const float* __restrict__ B,
                                                 const float* __restrict__ Pi,
                                                 const float* __restrict__ SP,
                                                 float* __restrict__ ws) {
  __shared__ __align__(16) float scr[4224];
  __shared__ __align__(16) float regB[4224];
  __shared__ __align__(16) float sPt[132];
  __shared__ int labs[425];
  const int t = threadIdx.x, lane = t & 31, grp = t >> 5;  // 16 groups
  const int s = blockIdx.x;
  int* wsi = (int*)ws;
  const float4* A4 = (const float4*)A;
  const float4* B4 = (const float4*)B;

  if (t < 16) wsi[IC2 + 32 * t] = 0;
  else if (t == 16) wsi[IROOT2] = 0;

  const float sv0 = SP[0], sv1 = SP[1], sv2 = SP[2], sv3 = SP[3];
  const float sp0 = __expf(sv0), sp1 = __expf(sv1), sp2 = __expf(sv2), sp3 = __expf(sv3);
  const float spsum = sp0 + sp1 + sp2 + sp3;
  const float spinv = 1.f / spsum;
  const float lss = __logf(spsum);
  float4 c4 = make_float4(0.f, 0.f, 0.f, 0.f);
  for (int i = 0; i < 32; ++i) {
    const float4 e = exp4f(A4[i * 32 + lane]);
    c4.x += e.x; c4.y += e.y; c4.z += e.z; c4.w += e.w;
  }
  const float4 inv4 = make_float4(sp0 * spinv / c4.x, sp1 * spinv / c4.y,
                                  sp2 * spinv / c4.z, sp3 * spinv / c4.w);
  const float4 sub4 = make_float4(__logf(c4.x) - (sv0 - lss), __logf(c4.y) - (sv1 - lss),
                                  __logf(c4.z) - (sv2 - lss), __logf(c4.w) - (sv3 - lss));
#pragma unroll
  for (int k = 0; k < 2; ++k) {
    const int i = grp * 2 + k;
    const float4 e = exp4f(A4[i * 32 + lane]);
    *(float4*)(scr + i * 132 + 4 * lane) =
        make_float4(e.x * inv4.x, e.y * inv4.y, e.z * inv4.z, e.w * inv4.w);
  }
#pragma unroll
  for (int rI = 0; rI < 2; ++rI) {
    const int i = grp + rI * 16;
    const float4 e = exp4f(B4[i * 32 + lane]);
    const float sinv = 1.f / rsum32(e.x + e.y + e.z + e.w);
    regB[(4 * lane + 0) * 33 + i] = e.x * sinv;
    regB[(4 * lane + 1) * 33 + i] = e.y * sinv;
    regB[(4 * lane + 2) * 33 + i] = e.z * sinv;
    regB[(4 * lane + 3) * 33 + i] = e.w * sinv;
  }
  if (grp < 4) {
    const float e = __expf(Pi[lane * 4 + grp]);
    sPt[grp * 33 + lane] = e / rsum32(e);
  } else if (grp == 4) {  // fill the 4 gap slots so persisted logs are finite
    if (lane < 4) sPt[lane * 33 + 32] = 1.f;
  }
  if (t < 84) {
    int g, d;
    if (t < 4) { g = 341 + 4 * s + t; d = 341 + t; }
    else if (t < 20) { g = 1365 + 16 * s + (t - 4); d = 345 + (t - 4); }
    else { g = 5461 + 64 * s + (t - 20); d = 361 + (t - 20); }
    labs[d] = labels[g];
  }
  if (t == 84) labs[85 + (s & 255)] = labels[85 + s];
  __syncthreads();

  // ---------- block 0: persist block-independent tables ----------
  if (s == 0) {
    for (int idx = t; idx < 4224; idx += 512) {
      ws[OFF_ASP + idx] = scr[idx];
      const float v = regB[idx];
      ws[OFF_RB + idx] = v;
      ws[OFF_LRB + idx] = __logf(v);
    }
    if (t < 132) ws[OFF_LSP + t] = __logf(sPt[t]);
#pragma unroll
    for (int k = 0; k < 2; ++k) {
      const int i = grp * 2 + k;
      const float4 av = A4[i * 32 + lane];
      const float4 e = exp4f(av);
      const float4 asp = make_float4(e.x * inv4.x, e.y * inv4.y,
                                     e.z * inv4.z, e.w * inv4.w);
      *(float4*)(ws + OFF_ALG + i * 128 + lane * 4) =
          make_float4(asp.x * (av.x - sub4.x), asp.y * (av.y - sub4.y),
                      asp.z * (av.z - sub4.z), asp.w * (av.w - sub4.w));
    }
  }
  W_DECL
  W_LOADUP
  __syncthreads();

  // ---------- phase 2: subtree up sweep; persist tbS rows + b4 ----------
  float* tbs = ws + OFF_TBO + s * 672;
  {
    const int q0 = grp, q1 = grp + 16, q2 = grp + 32, q3 = grp + 48;
    float v0 = sPt[(q0 & 3) * 33 + lane] * regB[labs[361 + q0] * 33 + lane];
    float v1 = sPt[(q1 & 3) * 33 + lane] * regB[labs[361 + q1] * 33 + lane];
    float v2 = sPt[(q2 & 3) * 33 + lane] * regB[labs[361 + q2] * 33 + lane];
    float v3 = sPt[(q3 & 3) * 33 + lane] * regB[labs[361 + q3] * 33 + lane];
    float s0 = v0, s1 = v1, s2 = v2, s3 = v3;
    rsum32x4(s0, s1, s2, s3);
    scr[(q0 >> 2) * 128 + lane * 4 + (q0 & 3)] = v0 / s0;
    scr[(q1 >> 2) * 128 + lane * 4 + (q1 & 3)] = v1 / s1;
    scr[(q2 >> 2) * 128 + lane * 4 + (q2 & 3)] = v2 / s2;
    scr[(q3 >> 2) * 128 + lane * 4 + (q3 & 3)] = v3 / s3;
  }
  __syncthreads();
  {  // S2: 16 L6 parents, ONE per group
    const int p = grp;
    float tb;
    DOT128M(tb, scr + p * 128)
    float bl = tb * regB[labs[345 + p] * 33 + lane];
    bl /= rsum32(bl);
    tbs[(5 + p) * 32 + lane] = tb;
    scr[2048 + (p >> 2) * 128 + lane * 4 + (p & 3)] = bl;  // X6
  }
  __syncthreads();
  if (grp < 4) {
    float tb;
    DOT128M(tb, scr + 2048 + grp * 128)
    float bl = tb * regB[labs[341 + grp] * 33 + lane];
    bl /= rsum32(bl);
    tbs[(1 + grp) * 32 + lane] = tb;
    scr[2560 + lane * 4 + grp] = bl;
  }
  __syncthreads();
  if (grp == 0) {
    float tb;
    DOT128M(tb, scr + 2560)
    float bl = tb * regB[labs[85 + (s & 255)] * 33 + lane];
    bl /= rsum32(bl);
    tbs[lane] = tb;
    ws[OFF_B4 + s * 32 + lane] = bl;
  }
}

__global__ __launch_bounds__(512, 1)
void k_down_p(const int* __restrict__ labels,
              const float* __restrict__ ws_c,
              float* __restrict__ ws,
              float* __restrict__ out) {
  __shared__ __align__(16) float scr[10240];   // 80 rows (P3 disjoint)
  __shared__ __align__(16) float regB[4224];
  __shared__ __align__(16) float sPt[132];
  __shared__ __align__(16) float tbrT[2720];
  __shared__ __align__(16) float tbS[672];
  __shared__ __align__(16) float ownb[32];
  __shared__ __align__(16) float r_buf[512];
  __shared__ int labs[425];
  __shared__ int fin;
  const int t = threadIdx.x, lane = t & 31, grp = t >> 5;  // 16 groups
  const int s = blockIdx.x;
  int* wsi = (int*)ws;
  double* partd = (double*)(ws + OFF_PART);
  (void)ws_c;

  // ---------- early prefetch: P3's b4 children ----------
  float pf0[8], pf1[8];
#pragma unroll
  for (int h = 0; h < 2; ++h) {
    const int p0 = grp + 32 * h, p1 = p0 + 16;
#pragma unroll
    for (int l = 0; l < 4; ++l) {
      pf0[h * 4 + l] = ws[OFF_B4 + (p0 * 4 + l) * 32 + lane];
      pf1[h * 4 + l] = ws[OFF_B4 + (p1 * 4 + l) * 32 + lane];
    }
  }
  // ---------- early prefetch: P4's ALG + logB tables into regs ----------
  const float4* wsALG4 = (const float4*)(ws + OFF_ALG);   // 1024 float4
  const float4* wsLRB4 = (const float4*)(ws + OFF_LRB);   // 1056 float4
  float4 pfA0 = wsALG4[t];
  float4 pfA1 = wsALG4[t + 512];
  float4 pfL0 = wsLRB4[t];
  float4 pfL1 = wsLRB4[t + 512];
  float4 pfL2 = make_float4(0.f, 0.f, 0.f, 0.f);
  if (t < 32) pfL2 = wsLRB4[t + 1024];

  // ---------- stage tables + per-block state from ws (float4) ------
  {
    const float4* wsASP4 = (const float4*)(ws + OFF_ASP);  // 1056 float4
    const float4* wsRB4 = (const float4*)(ws + OFF_RB);    // 1056 float4
    float4* scr4 = (float4*)scr;
    float4* regB4 = (float4*)regB;
    scr4[t] = wsASP4[t];
    scr4[t + 512] = wsASP4[t + 512];
    regB4[t] = wsRB4[t];
    regB4[t + 512] = wsRB4[t + 512];
    if (t < 32) {
      scr4[t + 1024] = wsASP4[t + 1024];
      regB4[t + 1024] = wsRB4[t + 1024];
    }
    if (t < 33) ((float4*)sPt)[t] = ((const float4*)(ws + OFF_LSP))[t];
    if (t < 168) ((float4*)tbS)[t] = ((const float4*)(ws + OFF_TBO + s * 672))[t];
    if (t < 8) ((float4*)ownb)[t] = ((const float4*)(ws + OFF_B4 + s * 32))[t];
  }
  for (int idx = t; idx < 341; idx += 512) labs[idx] = labels[idx];
  if (t < 84) {
    int g, d;
    if (t < 4) { g = 341 + 4 * s + t; d = 341 + t; }
    else if (t < 20) { g = 1365 + 16 * s + (t - 4); d = 345 + (t - 4); }
    else { g = 5461 + 64 * s + (t - 20); d = 361 + (t - 20); }
    labs[d] = labels[g];
  }
  __syncthreads();
  W_DECL
  W_LOADUP
  __syncthreads();

  // ---------- phase 3: top up sweep (rounds de-serialized) ----------
  {
#pragma unroll
    for (int h = 0; h < 2; ++h) {
      float* st0 = scr + h * 4096 + grp * 128;
      float* st1 = scr + h * 4096 + 2048 + grp * 128;
#pragma unroll
      for (int l = 0; l < 4; ++l) {
        st0[lane * 4 + l] = pf0[h * 4 + l];
        st1[lane * 4 + l] = pf1[h * 4 + l];
      }
    }
    const int pA0 = grp, pA1 = grp + 16, pB0 = grp + 32, pB1 = grp + 48;
    float tbA0, tbA1, tbB0, tbB1;
    DOT128X2M(tbA0, tbA1, scr + grp * 128, scr + 2048 + grp * 128)
    DOT128X2M(tbB0, tbB1, scr + 4096 + grp * 128, scr + 4096 + 2048 + grp * 128)
    float blA0 = tbA0 * regB[labs[21 + pA0] * 33 + lane];
    float blA1 = tbA1 * regB[labs[21 + pA1] * 33 + lane];
    float blB0 = tbB0 * regB[labs[21 + pB0] * 33 + lane];
    float blB1 = tbB1 * regB[labs[21 + pB1] * 33 + lane];
    float sA0 = blA0, sA1 = blA1, sB0 = blB0, sB1 = blB1;
    rsum32x4(sA0, sA1, sB0, sB1);
    blA0 /= sA0; blA1 /= sA1; blB0 /= sB0; blB1 /= sB1;
    tbrT[(21 + pA0) * 32 + lane] = tbA0;
    tbrT[(21 + pA1) * 32 + lane] = tbA1;
    tbrT[(21 + pB0) * 32 + lane] = tbB0;
    tbrT[(21 + pB1) * 32 + lane] = tbB1;
    scr[8192 + (pA0 >> 2) * 128 + lane * 4 + (pA0 & 3)] = blA0;  // bX3
    scr[8192 + (pA1 >> 2) * 128 + lane * 4 + (pA1 & 3)] = blA1;
    scr[8192 + (pB0 >> 2) * 128 + lane * 4 + (pB0 & 3)] = blB0;
    scr[8192 + (pB1 >> 2) * 128 + lane * 4 + (pB1 & 3)] = blB1;
  }
  __syncthreads();
  {  // L2: 16 parents, one per group
    const int p = grp;
    float tb;
    DOT128M(tb, scr + 8192 + p * 128)
    float bl = tb * regB[labs[5 + p] * 33 + lane];
    bl /= rsum32(bl);
    tbrT[(5 + p) * 32 + lane] = tb;
    scr[(p >> 2) * 128 + lane * 4 + (p & 3)] = bl;  // bX2 rows 0..3
  }
  __syncthreads();
  if (grp < 4) {  // L1: 4 parents
    float tb;
    DOT128M(tb, scr + grp * 128)
    float bl = tb * regB[labs[1 + grp] * 33 + lane];
    bl /= rsum32(bl);
    tbrT[(1 + grp) * 32 + lane] = tb;
    scr[512 + lane * 4 + grp] = bl;  // bX1 (row 4)
  }
  __syncthreads();
  if (grp == 0) { float tb; DOT128M(tb, scr + 512) tbrT[lane] = tb; }
  __syncthreads();

  // ---------- phase 4 (slim): write prefetched ALG + logB; reload W ------
  ((float4*)scr)[t] = pfA0;
  ((float4*)scr)[t + 512] = pfA1;
  ((float4*)regB)[t] = pfL0;
  ((float4*)regB)[t + 512] = pfL1;
  if (t < 32) ((float4*)regB)[t + 1024] = pfL2;
  if (grp < 8) {
    const float* wsASP_ = ws + OFF_ASP;
    REPW(WLDDN_B)
  }
  __syncthreads();

  // ---------- phase 5: distributed owners, step-gated ----------
  double ll = 0.0;
  float eps4own = 0.f;  // valid in grp 0
  if (grp < 4) {
    const int n1 = 1 + (s >> 6), n2 = 5 + (s >> 4), n3 = 21 + (s >> 2);
    const int a0 = s >> 6, a1 = (s >> 4) & 3, a2 = (s >> 2) & 3, a3 = s & 3;
    float w[4], uv[4];
    float* rb = r_buf + grp * 32;

    // ---- step 0 (all grps 0-3) ----
    float tbv = tbrT[lane];
    float bcv = tbv * __expf(regB[labs[0] * 33 + lane]);
    bcv /= rsum32(bcv);
    rb[lane] = bcv / tbv;
    if (grp == 0 && s == 0) {
      ll += (double)(bcv * regB[labs[0] * 33 + lane]);
      WU128M(w, uv, rb)
      const float lb0 = regB[labs[1] * 33 + lane], lb1 = regB[labs[2] * 33 + lane];
      const float lb2 = regB[labs[3] * 33 + lane], lb3 = regB[labs[4] * 33 + lane];
      float b0 = tbrT[1 * 32 + lane] * __expf(lb0);
      float b1 = tbrT[2 * 32 + lane] * __expf(lb1);
      float b2 = tbrT[3 * 32 + lane] * __expf(lb2);
      float b3 = tbrT[4 * 32 + lane] * __expf(lb3);
      float s0 = b0, s1 = b1, s2 = b2, s3 = b3;
      rsum32x4(s0, s1, s2, s3);
      b0 /= s0; b1 /= s1; b2 /= s2; b3 /= s3;
      ll += (double)(b0 * uv[0]) + (double)(b0 * w[0] * lb0);
      ll += (double)(b1 * uv[1]) + (double)(b1 * w[1] * lb1);
      ll += (double)(b2 * uv[2]) + (double)(b2 * w[2] * lb2);
      ll += (double)(b3 * uv[3]) + (double)(b3 * w[3] * lb3);
    } else {
      WONLY128M(w, rb)
    }

    // ---- step 1 (all grps 0-3) ----
    tbv = tbrT[n1 * 32 + lane];
    bcv = tbv * __expf(regB[labs[n1] * 33 + lane]);
    bcv /= rsum32(bcv);
    rb[lane] = (bcv * w[a0]) / tbv;
    if (grp == 1 && (s & 63) == 0) {
      WU128M(w, uv, rb)
      const int cb = 5 + 4 * (s >> 6);
      const float lb0 = regB[labs[cb + 0] * 33 + lane], lb1 = regB[labs[cb + 1] * 33 + lane];
      const float lb2 = regB[labs[cb + 2] * 33 + lane], lb3 = regB[labs[cb + 3] * 33 + lane];
      float b0 = tbrT[(cb + 0) * 32 + lane] * __expf(lb0);
      float b1 = tbrT[(cb + 1) * 32 + lane] * __expf(lb1);
      float b2 = tbrT[(cb + 2) * 32 + lane] * __expf(lb2);
      float b3 = tbrT[(cb + 3) * 32 + lane] * __expf(lb3);
      float s0 = b0, s1 = b1, s2 = b2, s3 = b3;
      rsum32x4(s0, s1, s2, s3);
      b0 /= s0; b1 /= s1; b2 /= s2; b3 /= s3;
      ll += (double)(b0 * uv[0]) + (double)(b0 * w[0] * lb0);
      ll += (double)(b1 * uv[1]) + (double)(b1 * w[1] * lb1);
      ll += (double)(b2 * uv[2]) + (double)(b2 * w[2] * lb2);
      ll += (double)(b3 * uv[3]) + (double)(b3 * w[3] * lb3);
    } else {
      WONLY128M(w, rb)
    }

    // ---- step 2 (grps 0,2,3 -- grp 1 done) ----
    if (grp != 1) {
      tbv = tbrT[n2 * 32 + lane];
      bcv = tbv * __expf(regB[labs[n2] * 33 + lane]);
      bcv /= rsum32(bcv);
      rb[lane] = (bcv * w[a1]) / tbv;
      if (grp == 2 && (s & 15) == 0) {
        WU128M(w, uv, rb)
        const int cb = 21 + 4 * (s >> 4);
        const float lb0 = regB[labs[cb + 0] * 33 + lane], lb1 = regB[labs[cb + 1] * 33 + lane];
        const float lb2 = regB[labs[cb + 2] * 33 + lane], lb3 = regB[labs[cb + 3] * 33 + lane];
        float b0 = tbrT[(cb + 0) * 32 + lane] * __expf(lb0);
        float b1 = tbrT[(cb + 1) * 32 + lane] * __expf(lb1);
        float b2 = tbrT[(cb + 2) * 32 + lane] * __expf(lb2);
        float b3 = tbrT[(cb + 3) * 32 + lane] * __expf(lb3);
        float s0 = b0, s1 = b1, s2 = b2, s3 = b3;
        rsum32x4(s0, s1, s2, s3);
        b0 /= s0; b1 /= s1; b2 /= s2; b3 /= s3;
        ll += (double)(b0 * uv[0]) + (double)(b0 * w[0] * lb0);
        ll += (double)(b1 * uv[1]) + (double)(b1 * w[1] * lb1);
        ll += (double)(b2 * uv[2]) + (double)(b2 * w[2] * lb2);
        ll += (double)(b3 * uv[3]) + (double)(b3 * w[3] * lb3);
      } else {
        WONLY128M(w, rb)
      }
    }

    // ---- step 3 (grps 0,3 -- grp 2 done) ----
    if (grp == 0 || grp == 3) {
      tbv = tbrT[n3 * 32 + lane];
      bcv = tbv * __expf(regB[labs[n3] * 33 + lane]);
      bcv /= rsum32(bcv);
      rb[lane] = (bcv * w[a2]) / tbv;
      if (grp == 3 && (s & 3) == 0) {
        WU128M(w, uv, rb)
        const int cb = s & ~3;
#pragma unroll
        for (int l = 0; l < 4; ++l) {
          const int ci = cb + l;
          const float bc = ws[OFF_B4 + ci * 32 + lane];
          const float e = bc * w[l];
          ll += (double)(bc * uv[l]) + (double)(e * regB[labs[85 + ci] * 33 + lane]);
        }
      } else {
        WONLY128M(w, rb)
      }
      eps4own = ownb[lane] * w[a3];
    }
  }
  __syncthreads();

  // ---------- phase 6: subtree down sweep ----------
  if (grp == 0) {
    r_buf[lane] = eps4own / tbS[lane];
    float w[4], u[4];
    WU128M(w, u, r_buf)
#pragma unroll
    for (int l = 0; l < 4; ++l) {
      const int lab = labs[341 + l];
      const float tbv = tbS[(1 + l) * 32 + lane];
      float bcv = tbv * __expf(regB[lab * 33 + lane]);
      bcv /= rsum32(bcv);
      const float e = bcv * w[l];
      ll += (double)(bcv * u[l]) + (double)(e * regB[lab * 33 + lane]);
      tbS[(1 + l) * 32 + lane] = e / tbv;
    }
  }
  __syncthreads();
  if (grp < 4) {
    const int p = grp;
    r_buf[p * 32 + lane] = tbS[(1 + p) * 32 + lane];
    float w[4], u[4];
    WU128M(w, u, r_buf + p * 32)
#pragma unroll
    for (int l = 0; l < 4; ++l) {
      const int q = p * 4 + l;
      const int lab = labs[345 + q];
      const float tbv = tbS[(5 + q) * 32 + lane];
      float bcv = tbv * __expf(regB[lab * 33 + lane]);
      bcv /= rsum32(bcv);
      const float e = bcv * w[l];
      ll += (double)(bcv * u[l]) + (double)(e * regB[lab * 33 + lane]);
      tbS[(5 + q) * 32 + lane] = e / tbv;
    }
  }
  __syncthreads();
  {  // d2: 16 L6 parents, one per group
    const int p = grp;
    float* rb0 = r_buf + grp * 32;
    rb0[lane] = tbS[(5 + p) * 32 + lane];
    float w[4], u[4];
    WU128M(w, u, rb0)
#pragma unroll
    for (int l = 0; l < 4; ++l) {
      const int q = p * 4 + l;
      const float lb = regB[labs[361 + q] * 33 + lane];
      const float lp = sPt[l * 33 + lane];
      float b = __expf(lp + lb);
      b /= rsum32(b);
      const float e = b * w[l];
      ll += (double)(b * u[l]) + (double)(e * lb) + (double)(e * lp);
    }
  }

  // ---------- phase 7: partials + tree finalize ----------
#pragma unroll
  for (int k = 32; k >= 1; k >>= 1) ll += __shfl_xor(ll, k);
  double* rbd = (double*)r_buf;
  __syncthreads();
  if ((t & 63) == 0) rbd[t >> 6] = ll;
  __syncthreads();
  if (t == 0) {
    partd[s] = ((rbd[0] + rbd[1]) + (rbd[2] + rbd[3])) +
               ((rbd[4] + rbd[5]) + (rbd[6] + rbd[7]));
    __threadfence();
    int f = 0;
    if (atomicAdd(&wsi[IC2 + 32 * (s >> 4)], 1) == 15)
      if (atomicAdd(&wsi[IROOT2], 1) == 15) f = 1;
    fin = f;
  }
  __syncthreads();
  if (fin) {
    __threadfence();
    if (t < 64) {
      double v = 0.0;
      for (int k = t; k < 256; k += 64) v += partd[k];
#pragma unroll
      for (int k = 32; k >= 1; k >>= 1) v += __shfl_xor(v, k);
      if (t == 0) out[0] = (float)v;
    }
  }
}

extern "C" void kernel_launch(void* const* d_in, const int* in_sizes, int n_in,
                              void* d_out, int out_size, void* d_ws, size_t ws_size,
                              hipStream_t stream) {
  (void)in_sizes; (void)n_in; (void)out_size;
  const int* labels = (const int*)d_in[0];
  const float* A = (const float*)d_in[1];
  const float* B = (const float*)d_in[2];
  const float* Pi = (const float*)d_in[3];
  const float* SP = (const float*)d_in[4];
  float* ws = (float*)d_ws;
  float* out = (float*)d_out;

  // ws_size is constant across calls -> host branch is graph-capture-safe.
  if (ws_size >= WS_NEED_BYTES) {
    hipLaunchKernelGGL(k_up_p, dim3(256), dim3(512), 0, stream,
                       labels, A, B, Pi, SP, ws);
    hipLaunchKernelGGL(k_down_p, dim3(256), dim3(512), 0, stream,
                       labels, ws, ws, out);
  } else {
    hipLaunchKernelGGL(k_up_f, dim3(256), dim3(256), 0, stream,
                       labels, A, B, Pi, SP, ws);
    hipLaunchKernelGGL(k_down_f, dim3(256), dim3(512), 0, stream,
                       labels, A, B, Pi, SP, ws, out);
  }
}